// Round 15
// baseline (278.272 us; speedup 1.0000x reference)
//
#include <hip/hip_runtime.h>
#include <math.h>

// Problem constants (B,N,F_IN,HID,OUT,H,D) = (32,512,256,512,512,4,128)
#define BATCH 32
#define NNODE 512
#define FIN   256
#define HIDC  512
#define OUTC  512
#define NHEAD 4
#define HDIM  128
#define EPSV  1e-5f
#define ALPHA_LR 0.2f

typedef _Float16 half8 __attribute__((ext_vector_type(8)));
typedef _Float16 half4v __attribute__((ext_vector_type(4)));
typedef float floatx4 __attribute__((ext_vector_type(4)));

#define GLOBAL_TO_LDS16(g, l)                                                  \
  __builtin_amdgcn_global_load_lds(                                            \
      (const __attribute__((address_space(1))) void*)(g),                      \
      (__attribute__((address_space(3))) void*)(l), 16, 0, 0)

// ---------------------------------------------------------------------------
// Generic 128x128 split-fp16 MFMA GEMM core — BK=64: stage two 32-K
// sub-chunks (16 loads), ONE drain barrier, 96 MFMAs, one trailing barrier.
// Accumulation order identical (sub 0 then sub 1) -> bit-identical output.
// LDS 64 KB (2 blocks/CU at grid 512). Chunk-XOR bank swizzle (round-2).
// ---------------------------------------------------------------------------
__device__ __forceinline__ void split_gemm_acc(
    const _Float16* __restrict__ Ah, const _Float16* __restrict__ Al, int lda,
    const _Float16* __restrict__ Bh, const _Float16* __restrict__ Bl, int ldb,
    int K, int rowBase, int colBase,
    _Float16* sAh, _Float16* sAl, _Float16* sBh, _Float16* sBl,
    floatx4 acc[4][4], int tid) {
  const int lane = tid & 63, wave = tid >> 6;
  const int wr = (wave >> 1) * 64, wc = (wave & 1) * 64;
  const int fr = lane & 15, q = lane >> 4;
  const int r = tid >> 2;
  const int cks = (((tid & 3) ^ ((r >> 1) & 3))) * 8;  // swizzled source chunk
  const int qx = (q ^ ((fr >> 1) & 3)) * 8;            // swizzled read chunk
  for (int k0 = 0; k0 < K; k0 += 64) {
#pragma unroll
    for (int s = 0; s < 2; ++s) {
      const int kc = k0 + s * 32;
      const int o = s * 4096;
      GLOBAL_TO_LDS16(&Ah[(size_t)(rowBase + r) * lda + kc + cks], &sAh[o + tid * 8]);
      GLOBAL_TO_LDS16(&Ah[(size_t)(rowBase + r + 64) * lda + kc + cks], &sAh[o + 2048 + tid * 8]);
      GLOBAL_TO_LDS16(&Al[(size_t)(rowBase + r) * lda + kc + cks], &sAl[o + tid * 8]);
      GLOBAL_TO_LDS16(&Al[(size_t)(rowBase + r + 64) * lda + kc + cks], &sAl[o + 2048 + tid * 8]);
      GLOBAL_TO_LDS16(&Bh[(size_t)(colBase + r) * ldb + kc + cks], &sBh[o + tid * 8]);
      GLOBAL_TO_LDS16(&Bh[(size_t)(colBase + r + 64) * ldb + kc + cks], &sBh[o + 2048 + tid * 8]);
      GLOBAL_TO_LDS16(&Bl[(size_t)(colBase + r) * ldb + kc + cks], &sBl[o + tid * 8]);
      GLOBAL_TO_LDS16(&Bl[(size_t)(colBase + r + 64) * ldb + kc + cks], &sBl[o + 2048 + tid * 8]);
    }
    __syncthreads();
#pragma unroll
    for (int s = 0; s < 2; ++s) {
      const int o = s * 4096;
      half8 ah[4], al4[4], bh[4], bl4[4];
#pragma unroll
      for (int i = 0; i < 4; ++i) {
        ah[i]  = *(const half8*)&sAh[o + (wr + i * 16 + fr) * 32 + qx];
        al4[i] = *(const half8*)&sAl[o + (wr + i * 16 + fr) * 32 + qx];
      }
#pragma unroll
      for (int j = 0; j < 4; ++j) {
        bh[j]  = *(const half8*)&sBh[o + (wc + j * 16 + fr) * 32 + qx];
        bl4[j] = *(const half8*)&sBl[o + (wc + j * 16 + fr) * 32 + qx];
      }
#pragma unroll
      for (int i = 0; i < 4; ++i)
#pragma unroll
        for (int j = 0; j < 4; ++j) {
          acc[i][j] = __builtin_amdgcn_mfma_f32_16x16x32_f16(al4[i], bh[j], acc[i][j], 0, 0, 0);
          acc[i][j] = __builtin_amdgcn_mfma_f32_16x16x32_f16(ah[i], bl4[j], acc[i][j], 0, 0, 0);
          acc[i][j] = __builtin_amdgcn_mfma_f32_16x16x32_f16(ah[i], bh[j], acc[i][j], 0, 0, 0);
        }
    }
    __syncthreads();
  }
}

// ---------------------------------------------------------------------------
// Prep: splits + conv weight transform + OP halo zero.
// ---------------------------------------------------------------------------
__global__ __launch_bounds__(256) void k_prep(
    const float* __restrict__ adj, const float* __restrict__ gcw,
    const float* __restrict__ gatw, const float* __restrict__ cw,
    _Float16* __restrict__ ADJh, _Float16* __restrict__ ADJl,
    _Float16* __restrict__ GWh, _Float16* __restrict__ GWl,
    _Float16* __restrict__ GAh, _Float16* __restrict__ GAl,
    _Float16* __restrict__ WT, _Float16* __restrict__ OP) {
  const int i = blockIdx.x * 256 + threadIdx.x;
  if (i < 262144) {
    float v = adj[i];
    _Float16 h = (_Float16)v;
    ADJh[i] = h; ADJl[i] = (_Float16)(v - (float)h);
  } else if (i < 393216) {
    int j = i - 262144;
    int n = j >> 8, k = j & 255;
    float v = gcw[(size_t)k * HIDC + n];
    _Float16 h = (_Float16)v;
    GWh[j] = h; GWl[j] = (_Float16)(v - (float)h);
  } else if (i < 655360) {
    int j = i - 393216;
    float v = gatw[j];
    _Float16 h = (_Float16)v;
    GAh[j] = h; GAl[j] = (_Float16)(v - (float)h);
  } else if (i < 1441792) {
    int j = i - 655360;
    int n = j / 1536, kk = j - n * 1536;
    int tap = kk >> 9, ci = kk & 511;
    WT[j] = (_Float16)cw[(size_t)n * 1536 + ci * 3 + tap];
  } else if (i < 1474560) {
    int j = i - 1441792;
    int b = j >> 10, rs = (j >> 9) & 1, c = j & 511;
    OP[((size_t)b * 514 + rs * 513) * OUTC + c] = (_Float16)0.f;
  }
}

// ---------------------------------------------------------------------------
// x [b][m=512][f=256] fp32 -> transposed split XT[b][f][m] hi/lo fp16.
// LDS 64x64 tile transpose, pad 65 (conflict-free), coalesced both sides.
// ---------------------------------------------------------------------------
__global__ __launch_bounds__(256) void k_xsplit_t(const float* __restrict__ X,
                                                  _Float16* __restrict__ XTh,
                                                  _Float16* __restrict__ XTl) {
  __shared__ float sT[64][65];
  const int bt = blockIdx.x;          // 0..1023
  const int ft = bt & 3;              // 4 f-tiles of 64
  const int mt = (bt >> 2) & 7;       // 8 m-tiles of 64
  const int b  = bt >> 5;             // 32 batches
  const int tid = threadIdx.x;
  const int rr = tid >> 4, cc4 = (tid & 15) * 4;
#pragma unroll
  for (int it = 0; it < 4; ++it) {
    int m = rr + it * 16;
    float4 v = *(const float4*)&X[((size_t)(b * 512 + mt * 64 + m)) * 256 + ft * 64 + cc4];
    sT[m][cc4] = v.x; sT[m][cc4 + 1] = v.y; sT[m][cc4 + 2] = v.z; sT[m][cc4 + 3] = v.w;
  }
  __syncthreads();
#pragma unroll
  for (int it = 0; it < 4; ++it) {
    int f = rr + it * 16;
    half4v h, l;
#pragma unroll
    for (int e = 0; e < 4; ++e) {
      float v = sT[cc4 + e][f];
      _Float16 hh = (_Float16)v;
      h[e] = hh; l[e] = (_Float16)(v - (float)hh);
    }
    size_t base = ((size_t)b * 256 + ft * 64 + f) * 512 + mt * 64 + cc4;
    *(half4v*)&XTh[base] = h;
    *(half4v*)&XTl[base] = l;
  }
}

// ---------------------------------------------------------------------------
// AX = adj @ x per batch: C[bn, f] = sum_m adj[n,m] x[b,m,f].
// 128x64 tile, grid 512 = 2/CU. BK=64. LDS 48 KB. T1 XCD swizzle.
// ---------------------------------------------------------------------------
__global__ __launch_bounds__(256) void k_ax(
    const _Float16* __restrict__ ADJh, const _Float16* __restrict__ ADJl,
    const _Float16* __restrict__ XTh, const _Float16* __restrict__ XTl,
    _Float16* __restrict__ AXh, _Float16* __restrict__ AXl) {
  __shared__ _Float16 sAh[8192], sAl[8192], sBh[4096], sBl[4096];
  const int tid = threadIdx.x;
  const int lane = tid & 63, wave = tid >> 6;
  const int fr = lane & 15, q = lane >> 4;
  const int r = tid >> 2;
  const int cks = (((tid & 3) ^ ((r >> 1) & 3))) * 8;
  const int qx = (q ^ ((fr >> 1) & 3)) * 8;
  const int id = blockIdx.y * 4 + blockIdx.x;  // 0..511
  const int jj = id >> 3;
  const int rowBase = ((id & 7) * 16 + (jj >> 2)) * 128;  // global bn row
  const int colBase = (jj & 3) * 64;                      // f col
  const int b = rowBase >> 9;
  const int nrow = rowBase & 511;
  const _Float16* Bh = XTh + (size_t)b * FIN * NNODE;
  const _Float16* Bl = XTl + (size_t)b * FIN * NNODE;
  floatx4 acc[2][4] = {};
  for (int k0 = 0; k0 < NNODE; k0 += 64) {
#pragma unroll
    for (int s = 0; s < 2; ++s) {
      const int kc = k0 + s * 32;
      const int oA = s * 4096, oB = s * 2048;
      GLOBAL_TO_LDS16(&ADJh[(size_t)(nrow + r) * NNODE + kc + cks], &sAh[oA + tid * 8]);
      GLOBAL_TO_LDS16(&ADJh[(size_t)(nrow + r + 64) * NNODE + kc + cks], &sAh[oA + 2048 + tid * 8]);
      GLOBAL_TO_LDS16(&ADJl[(size_t)(nrow + r) * NNODE + kc + cks], &sAl[oA + tid * 8]);
      GLOBAL_TO_LDS16(&ADJl[(size_t)(nrow + r + 64) * NNODE + kc + cks], &sAl[oA + 2048 + tid * 8]);
      GLOBAL_TO_LDS16(&Bh[(size_t)(colBase + r) * NNODE + kc + cks], &sBh[oB + tid * 8]);
      GLOBAL_TO_LDS16(&Bl[(size_t)(colBase + r) * NNODE + kc + cks], &sBl[oB + tid * 8]);
    }
    __syncthreads();
#pragma unroll
    for (int s = 0; s < 2; ++s) {
      const int oA = s * 4096, oB = s * 2048;
      half8 ah[2], al4[2], bh[4], bl4[4];
#pragma unroll
      for (int i = 0; i < 2; ++i) {
        ah[i]  = *(const half8*)&sAh[oA + (wave * 32 + i * 16 + fr) * 32 + qx];
        al4[i] = *(const half8*)&sAl[oA + (wave * 32 + i * 16 + fr) * 32 + qx];
      }
#pragma unroll
      for (int j = 0; j < 4; ++j) {
        bh[j]  = *(const half8*)&sBh[oB + (j * 16 + fr) * 32 + qx];
        bl4[j] = *(const half8*)&sBl[oB + (j * 16 + fr) * 32 + qx];
      }
#pragma unroll
      for (int i = 0; i < 2; ++i)
#pragma unroll
        for (int j = 0; j < 4; ++j) {
          acc[i][j] = __builtin_amdgcn_mfma_f32_16x16x32_f16(al4[i], bh[j], acc[i][j], 0, 0, 0);
          acc[i][j] = __builtin_amdgcn_mfma_f32_16x16x32_f16(ah[i], bl4[j], acc[i][j], 0, 0, 0);
          acc[i][j] = __builtin_amdgcn_mfma_f32_16x16x32_f16(ah[i], bh[j], acc[i][j], 0, 0, 0);
        }
    }
    __syncthreads();
  }
#pragma unroll
  for (int i = 0; i < 2; ++i) {
    const int r0 = rowBase + wave * 32 + i * 16 + q * 4;
#pragma unroll
    for (int rg = 0; rg < 4; ++rg) {
      size_t base = (size_t)(r0 + rg) * FIN + colBase + fr;
#pragma unroll
      for (int j = 0; j < 4; ++j) {
        float v = acc[i][j][rg];
        _Float16 h = (_Float16)v;
        AXh[base + j * 16] = h;
        AXl[base + j * 16] = (_Float16)(v - (float)h);
      }
    }
  }
}

// ---------------------------------------------------------------------------
// g = relu(bn1(AX @ gc_w + gc_b)). M=16384, N=512, K=256. T1 XCD swizzle.
// ---------------------------------------------------------------------------
__global__ __launch_bounds__(256) void k_gcn2(
    const _Float16* __restrict__ AXh, const _Float16* __restrict__ AXl,
    const _Float16* __restrict__ GWh, const _Float16* __restrict__ GWl,
    const float* __restrict__ gcb, const float* __restrict__ g1,
    const float* __restrict__ b1, const float* __restrict__ m1,
    const float* __restrict__ v1,
    _Float16* __restrict__ Gh, _Float16* __restrict__ Gl) {
  __shared__ _Float16 sm[4][8192];   // BK=64 (64 KB)
  const int tid = threadIdx.x;
  const int id = blockIdx.y * 4 + blockIdx.x;  // 0..511
  const int jj = id >> 3;
  const int rowBase = ((id & 7) * 16 + (jj >> 2)) * 128;
  const int colBase = (jj & 3) * 128;
  floatx4 acc[4][4] = {};
  split_gemm_acc(AXh, AXl, FIN, GWh, GWl, FIN, FIN, rowBase, colBase,
                 sm[0], sm[1], sm[2], sm[3], acc, tid);
  const int lane = tid & 63, wave = tid >> 6;
  const int wr = (wave >> 1) * 64, wc = (wave & 1) * 64;
  const int fr = lane & 15, q = lane >> 4;
  float sc[4], of[4];
#pragma unroll
  for (int j = 0; j < 4; ++j) {
    int c = colBase + wc + j * 16 + fr;
    float s = g1[c] * rsqrtf(v1[c] + EPSV);
    sc[j] = s;
    of[j] = (gcb[c] - m1[c]) * s + b1[c];
  }
#pragma unroll
  for (int i = 0; i < 4; ++i) {
    const int r0 = rowBase + wr + i * 16 + q * 4;
#pragma unroll
    for (int rg = 0; rg < 4; ++rg) {
      size_t base = (size_t)(r0 + rg) * HIDC + colBase + wc + fr;
#pragma unroll
      for (int j = 0; j < 4; ++j) {
        float v = fmaxf(fmaf(acc[i][j][rg], sc[j], of[j]), 0.0f);
        _Float16 h = (_Float16)v;
        Gh[base + j * 16] = h;
        Gl[base + j * 16] = (_Float16)(v - (float)h);
      }
    }
  }
}

// ---------------------------------------------------------------------------
// hh = g @ gat_w^T : M=16384 N=512 K=512. Split output + fused transposed
// V write (HHT != nullptr). T1 XCD swizzle.
// ---------------------------------------------------------------------------
__global__ __launch_bounds__(256) void k_hh(
    const _Float16* __restrict__ Gh, const _Float16* __restrict__ Gl,
    const _Float16* __restrict__ GAh, const _Float16* __restrict__ GAl,
    _Float16* __restrict__ HHh, _Float16* __restrict__ HHl,
    _Float16* __restrict__ HHT) {
  __shared__ _Float16 sm[4][8192];   // BK=64 (64 KB)
  const int tid = threadIdx.x;
  const int id = blockIdx.y * 4 + blockIdx.x;  // 0..511
  const int jj = id >> 3;
  const int rowBase = ((id & 7) * 16 + (jj >> 2)) * 128;
  const int colBase = (jj & 3) * 128;
  floatx4 acc[4][4] = {};
  split_gemm_acc(Gh, Gl, HIDC, GAh, GAl, HIDC, HIDC, rowBase, colBase,
                 sm[0], sm[1], sm[2], sm[3], acc, tid);
  const int lane = tid & 63, wave = tid >> 6;
  const int wr = (wave >> 1) * 64, wc = (wave & 1) * 64;
  const int fr = lane & 15, q = lane >> 4;
#pragma unroll
  for (int i = 0; i < 4; ++i) {
    const int r0 = rowBase + wr + i * 16 + q * 4;
    const int node = r0 & 511;
    const int bbv = r0 >> 9;
#pragma unroll
    for (int j = 0; j < 4; ++j) {
      const int c = colBase + wc + j * 16 + fr;   // = h*128 + d
      half4v v4;
#pragma unroll
      for (int rg = 0; rg < 4; ++rg) {
        float v = acc[i][j][rg];
        _Float16 h = (_Float16)v;
        size_t base = (size_t)(r0 + rg) * OUTC + c;
        HHh[base] = h;
        HHl[base] = (_Float16)(v - (float)h);
        v4[rg] = h;
      }
      if (HHT)
        *(half4v*)&HHT[((size_t)(bbv * 4 + (c >> 7)) * 128 + (c & 127)) * 512 + node] = v4;
    }
  }
}

// ---------------------------------------------------------------------------
// k_vt fallback (small workspace): HHT[(bb*4+h)*128+d][node] = HHh[...].
// ---------------------------------------------------------------------------
__global__ __launch_bounds__(256) void k_vt(const _Float16* __restrict__ HHh,
                                            _Float16* __restrict__ HHT) {
  __shared__ _Float16 sT[128 * 132];
  const int bt = blockIdx.x;           // 0..511
  const int nt = bt & 3, g = bt >> 2;  // g = bb*4+h
  const int bb = g >> 2, h = g & 3;
  const int tid = threadIdx.x;
  const int rr = tid >> 4, cc = (tid & 15) * 8;
#pragma unroll
  for (int it = 0; it < 8; ++it) {
    int node = rr + it * 16;
    half8 v = *(const half8*)&HHh[((size_t)bb * 512 + nt * 128 + node) * 512 + h * 128 + cc];
#pragma unroll
    for (int e = 0; e < 8; ++e) sT[(cc + e) * 132 + node] = v[e];
  }
  __syncthreads();
#pragma unroll
  for (int it = 0; it < 8; ++it) {
    int d = rr + it * 16;
    half8 v;
#pragma unroll
    for (int e = 0; e < 8; ++e) v[e] = sT[d * 132 + cc + e];
    *(half8*)&HHT[((size_t)g * 128 + d) * 512 + nt * 128 + cc] = v;
  }
}

// ---------------------------------------------------------------------------
// Fused flash attention — round-7 proven form: round-2 schedule (4 plain
// barriers/kt, V overlays dead K, chunk-XOR swizzle) with 128 q-rows/block,
// grid 512. K/V fragments shared by the 2 m-tiles.
// ---------------------------------------------------------------------------
__global__ __launch_bounds__(256, 2) void k_attn(
    const _Float16* __restrict__ HHh, const _Float16* __restrict__ HHl,
    const _Float16* __restrict__ HHT, _Float16* __restrict__ OP) {
  __shared__ _Float16 sK[8][2048];   // tiles 0-3: K hi (k0=0..3), 4-7: K lo
  __shared__ _Float16 sP[128 * 68];  // [qrow][64 keys] stride 68
  _Float16* sV = &sK[0][0];          // V overlays dead K region after QK burst
  const int tid = threadIdx.x;
  const int lane = tid & 63, wave = tid >> 6;
  const int fr = lane & 15, q = lane >> 4;
  const int id = blockIdx.x;          // 0..511
  const int slot = id >> 3;           // 0..63
  const int g = (id & 7) + 8 * (slot >> 2);   // 0..127
  const int qBase = (slot & 3) * 128;
  const int bb = g >> 2, h = g & 3;
  const int w32 = wave * 32;
  const _Float16* Qh = HHh + (size_t)bb * NNODE * OUTC + h * HDIM;
  const _Float16* Ql = HHl + (size_t)bb * NNODE * OUTC + h * HDIM;
  const _Float16* VT = HHT + (size_t)g * HDIM * NNODE;  // [128 d][512 nodes]
  const int rk = tid >> 2;
  const int cks = (((tid & 3) ^ ((rk >> 1) & 3))) * 8;  // swizzled src chunk
  const int qx = (q ^ ((fr >> 1) & 3)) * 8;             // swizzled read chunk

  // Q fragments in registers: 2 m-tiles x 4 k0 (hi+lo), loaded once.
  half8 qh[2][4], ql[2][4];
#pragma unroll
  for (int m = 0; m < 2; ++m)
#pragma unroll
    for (int k0 = 0; k0 < 4; ++k0) {
      const size_t off = (size_t)(qBase + w32 + m * 16 + fr) * OUTC + k0 * 32 + q * 8;
      qh[m][k0] = *(const half8*)&Qh[off];
      ql[m][k0] = *(const half8*)&Ql[off];
    }

  floatx4 oacc[2][8] = {};
  float m_i[2][4], l_i[2][4];
#pragma unroll
  for (int m = 0; m < 2; ++m)
#pragma unroll
    for (int rg = 0; rg < 4; ++rg) { m_i[m][rg] = -1e30f; l_i[m][rg] = 0.f; }

  for (int kt = 0; kt < 8; ++kt) {
    const int ktb = kt * 64;
    // ---- stage whole 64-key K-tile (hi+lo, 32 KB, 8 sub-tiles) ----
#pragma unroll
    for (int t = 0; t < 4; ++t) {
      GLOBAL_TO_LDS16(&Qh[(size_t)(ktb + rk) * OUTC + t * 32 + cks], &sK[t][tid * 8]);
      GLOBAL_TO_LDS16(&Ql[(size_t)(ktb + rk) * OUTC + t * 32 + cks], &sK[4 + t][tid * 8]);
    }
    __syncthreads();
    // ---- S = Q @ K^T: 96-MFMA burst, K fragments shared across m ----
    floatx4 sacc[2][4] = {};
#pragma unroll
    for (int k0 = 0; k0 < 4; ++k0)
#pragma unroll
      for (int j = 0; j < 4; ++j) {
        half8 bh = *(const half8*)&sK[k0][(j * 16 + fr) * 32 + qx];
        half8 bl = *(const half8*)&sK[4 + k0][(j * 16 + fr) * 32 + qx];
#pragma unroll
        for (int m = 0; m < 2; ++m) {
          sacc[m][j] = __builtin_amdgcn_mfma_f32_16x16x32_f16(ql[m][k0], bh, sacc[m][j], 0, 0, 0);
          sacc[m][j] = __builtin_amdgcn_mfma_f32_16x16x32_f16(qh[m][k0], bl, sacc[m][j], 0, 0, 0);
          sacc[m][j] = __builtin_amdgcn_mfma_f32_16x16x32_f16(qh[m][k0], bh, sacc[m][j], 0, 0, 0);
        }
      }
    __syncthreads();   // sK fully consumed; safe to overlay with V
    // ---- LeakyReLU + online softmax (both m-tiles) ----
#pragma unroll
    for (int m = 0; m < 2; ++m) {
#pragma unroll
      for (int j = 0; j < 4; ++j)
#pragma unroll
        for (int rg = 0; rg < 4; ++rg) {
          float v = sacc[m][j][rg];
          sacc[m][j][rg] = v > 0.f ? v : ALPHA_LR * v;
        }
#pragma unroll
      for (int rg = 0; rg < 4; ++rg) {
        float mx = sacc[m][0][rg];
#pragma unroll
        for (int j = 1; j < 4; ++j) mx = fmaxf(mx, sacc[m][j][rg]);
        mx = fmaxf(mx, __shfl_xor(mx, 1));
        mx = fmaxf(mx, __shfl_xor(mx, 2));
        mx = fmaxf(mx, __shfl_xor(mx, 4));
        mx = fmaxf(mx, __shfl_xor(mx, 8));
        float mnew = fmaxf(m_i[m][rg], mx);
        float alpha = __expf(m_i[m][rg] - mnew);
        m_i[m][rg] = mnew;
        float sum = 0.f;
#pragma unroll
        for (int j = 0; j < 4; ++j) {
          float p = __expf(sacc[m][j][rg] - mnew);
          sacc[m][j][rg] = p;
          sum += p;
        }
        sum += __shfl_xor(sum, 1);
        sum += __shfl_xor(sum, 2);
        sum += __shfl_xor(sum, 4);
        sum += __shfl_xor(sum, 8);
        l_i[m][rg] = l_i[m][rg] * alpha + sum;
#pragma unroll
        for (int j = 0; j < 8; ++j) oacc[m][j][rg] *= alpha;   // ALL 8 d-cols
      }
    }
    // ---- stage V (2 ks-tiles from HHT, overlays sK) + write P ----
#pragma unroll
    for (int l = 0; l < 4; ++l)
      GLOBAL_TO_LDS16(&VT[(size_t)((l >> 1) * 64 + rk) * NNODE + ktb + (l & 1) * 32 + cks],
                      &sV[(l & 1) * 4096 + (l >> 1) * 2048 + tid * 8]);
#pragma unroll
    for (int m = 0; m < 2; ++m)
#pragma unroll
      for (int j = 0; j < 4; ++j)
#pragma unroll
        for (int rg = 0; rg < 4; ++rg)
          sP[(w32 + m * 16 + q * 4 + rg) * 68 + j * 16 + fr] = (_Float16)sacc[m][j][rg];
    __syncthreads();
    // ---- O += P @ V: 32-MFMA burst, V fragments shared across m ----
#pragma unroll
    for (int ks = 0; ks < 2; ++ks) {
      half8 pa0 = *(const half8*)&sP[(w32 + fr) * 68 + ks * 32 + q * 8];
      half8 pa1 = *(const half8*)&sP[(w32 + 16 + fr) * 68 + ks * 32 + q * 8];
#pragma unroll
      for (int j = 0; j < 8; ++j) {
        half8 bv = *(const half8*)&sV[ks * 4096 + (j * 16 + fr) * 32 + qx];
        oacc[0][j] = __builtin_amdgcn_mfma_f32_16x16x32_f16(pa0, bv, oacc[0][j], 0, 0, 0);
        oacc[1][j] = __builtin_amdgcn_mfma_f32_16x16x32_f16(pa1, bv, oacc[1][j], 0, 0, 0);
      }
    }
    __syncthreads();   // sV dead before next kt's K staging
  }
  // ---- normalize + write into padded conv input ----
#pragma unroll
  for (int m = 0; m < 2; ++m)
#pragma unroll
    for (int rg = 0; rg < 4; ++rg) {
      const float inv = 1.0f / l_i[m][rg];
      const int node = qBase + w32 + m * 16 + q * 4 + rg;
      size_t base = ((size_t)bb * 514 + 1 + node) * OUTC + h * HDIM + fr;
#pragma unroll
      for (int j = 0; j < 8; ++j)
        OP[base + j * 16] = (_Float16)(oacc[m][j][rg] * inv);
    }
}

// ---------------------------------------------------------------------------
// y = relu(bn2(conv1d(o)+conv_b)) via fp16 MFMA GEMM, XCD-swizzled.
// BK=64 (two 32-K sub-chunks per barrier pair), 32 MFMAs/step. LDS 32 KB.
// ---------------------------------------------------------------------------
__global__ __launch_bounds__(256) void k_conv_mfma(
    const _Float16* __restrict__ OP, const _Float16* __restrict__ WT,
    const float* __restrict__ cb, const float* __restrict__ g2,
    const float* __restrict__ b2, const float* __restrict__ m2,
    const float* __restrict__ v2, float* __restrict__ Y) {
  __shared__ _Float16 At[8192];
  __shared__ _Float16 Bt[8192];
  const int tid = threadIdx.x;
  const int lane = tid & 63, wave = tid >> 6;
  const int wr = (wave >> 1) * 64, wc = (wave & 1) * 64;
  const int id = blockIdx.y * 4 + blockIdx.x;
  const int jj = id >> 3;
  const int rowBase = ((id & 7) * 16 + (jj >> 2)) * 128;
  const int colBase = (jj & 3) * 128;
  const int b = rowBase >> 9;
  const int n0 = rowBase & 511;
  const int r = tid >> 2;
  const int cks = (((tid & 3) ^ ((r >> 1) & 3))) * 8;
  const int fr = lane & 15, q = lane >> 4;
  const int qx = (q ^ ((fr >> 1) & 3)) * 8;
  floatx4 acc[4][4] = {};
  for (int k0 = 0; k0 < 3 * OUTC; k0 += 64) {
#pragma unroll
    for (int s = 0; s < 2; ++s) {
      const int kc = k0 + s * 32;
      const int o = s * 4096;
      const int tap = kc >> 9;
      const int cib = kc & 511;
      const size_t abase = ((size_t)b * 514 + n0 + tap) * OUTC + cib + cks;
      GLOBAL_TO_LDS16(&OP[abase + (size_t)r * OUTC],        &At[o + tid * 8]);
      GLOBAL_TO_LDS16(&OP[abase + (size_t)(r + 64) * OUTC], &At[o + 2048 + tid * 8]);
      GLOBAL_TO_LDS16(&WT[(size_t)(colBase + r) * 1536 + kc + cks],      &Bt[o + tid * 8]);
      GLOBAL_TO_LDS16(&WT[(size_t)(colBase + r + 64) * 1536 + kc + cks], &Bt[o + 2048 + tid * 8]);
    }
    __syncthreads();
#pragma unroll
    for (int s = 0; s < 2; ++s) {
      const int o = s * 4096;
      half8 af[4], bf[4];
#pragma unroll
      for (int i = 0; i < 4; ++i)
        af[i] = *(const half8*)&At[o + (wr + i * 16 + fr) * 32 + qx];
#pragma unroll
      for (int j = 0; j < 4; ++j)
        bf[j] = *(const half8*)&Bt[o + (wc + j * 16 + fr) * 32 + qx];
#pragma unroll
      for (int i = 0; i < 4; ++i)
#pragma unroll
        for (int j = 0; j < 4; ++j)
          acc[i][j] = __builtin_amdgcn_mfma_f32_16x16x32_f16(af[i], bf[j], acc[i][j], 0, 0, 0);
    }
    __syncthreads();
  }
  float sc[4], of[4];
#pragma unroll
  for (int j = 0; j < 4; ++j) {
    int c = colBase + wc + j * 16 + fr;
    float s = g2[c] * rsqrtf(v2[c] + EPSV);
    sc[j] = s;
    of[j] = (cb[c] - m2[c]) * s + b2[c];
  }
#pragma unroll
  for (int i = 0; i < 4; ++i) {
    const int R0r = rowBase + wr + i * 16 + q * 4;
#pragma unroll
    for (int rg = 0; rg < 4; ++rg) {
      float* dst = &Y[(size_t)(R0r + rg) * OUTC + colBase + wc + fr];
#pragma unroll
      for (int j = 0; j < 4; ++j)
        dst[j * 16] = fmaxf(fmaf(acc[i][j][rg], sc[j], of[j]), 0.0f);
    }
  }
}

// ---------------------------------------------------------------------------
extern "C" void kernel_launch(void* const* d_in, const int* in_sizes, int n_in,
                              void* d_out, int out_size, void* d_ws, size_t ws_size,
                              hipStream_t stream) {
  const float* x     = (const float*)d_in[0];
  const float* adj   = (const float*)d_in[1];
  const float* gc_w  = (const float*)d_in[2];
  const float* gc_b  = (const float*)d_in[3];
  const float* bn1_g = (const float*)d_in[4];
  const float* bn1_b = (const float*)d_in[5];
  const float* bn1_m = (const float*)d_in[6];
  const float* bn1_v = (const float*)d_in[7];
  const float* gat_w = (const float*)d_in[8];
  const float* conv_w= (const float*)d_in[9];
  const float* conv_b= (const float*)d_in[10];
  const float* bn2_g = (const float*)d_in[11];
  const float* bn2_b = (const float*)d_in[12];
  const float* bn2_m = (const float*)d_in[13];
  const float* bn2_v = (const float*)d_in[14];
  float* out = (float*)d_out;

  char* ws = (char*)d_ws;
  _Float16* AXh = (_Float16*)(ws + 0);          // 8 MB [16384,256]
  _Float16* AXl = (_Float16*)(ws + 16777216);   // 8 MB
  _Float16* HHh = (_Float16*)(ws + 0);          // reuse after AX dead
  _Float16* HHl = (_Float16*)(ws + 16777216);
  _Float16* XTh = (_Float16*)(ws + 33554432);   // 8 MB [32][256][512]
  _Float16* XTl = (_Float16*)(ws + 41943040);   // 8 MB
  _Float16* Gh  = (_Float16*)(ws + 33554432);   // reuse after XT dead
  _Float16* Gl  = (_Float16*)(ws + 50331648);
  _Float16* OP  = (_Float16*)(ws + 67108864);
  _Float16* WT  = (_Float16*)(ws + 83951616);
  _Float16* ADJh= (_Float16*)(ws + 85524480);
  _Float16* ADJl= (_Float16*)(ws + 86048768);
  _Float16* GWh = (_Float16*)(ws + 86573056);
  _Float16* GWl = (_Float16*)(ws + 86835200);
  _Float16* GAh = (_Float16*)(ws + 87097344);
  _Float16* GAl = (_Float16*)(ws + 87621632);

  // HHT placement: fused path needs a region NOT aliasing Gh/Gl (k_hh reads
  // G while writing HHT). If the workspace has room past the static
  // allocations, put HHT there and fuse; else fall back to separate k_vt.
  const bool fused = ws_size >= (size_t)(88145920 + 16777216);
  _Float16* HHT = fused ? (_Float16*)(ws + 88145920)
                        : (_Float16*)(ws + 33554432);

  k_prep<<<5760, 256, 0, stream>>>(adj, gc_w, gat_w, conv_w,
                                   ADJh, ADJl, GWh, GWl, GAh, GAl, WT, OP);
  k_xsplit_t<<<1024, 256, 0, stream>>>(x, XTh, XTl);
  k_ax<<<dim3(4, 128), 256, 0, stream>>>(ADJh, ADJl, XTh, XTl, AXh, AXl);
  k_gcn2<<<dim3(4, 128), 256, 0, stream>>>(AXh, AXl, GWh, GWl, gc_b,
                                           bn1_g, bn1_b, bn1_m, bn1_v, Gh, Gl);
  if (fused) {
    k_hh<<<dim3(4, 128), 256, 0, stream>>>(Gh, Gl, GAh, GAl, HHh, HHl, HHT);
  } else {
    k_hh<<<dim3(4, 128), 256, 0, stream>>>(Gh, Gl, GAh, GAl, HHh, HHl,
                                           (_Float16*)nullptr);
    k_vt<<<512, 256, 0, stream>>>(HHh, HHT);
  }
  k_attn<<<512, 256, 0, stream>>>(HHh, HHl, HHT, OP);
  k_conv_mfma<<<dim3(4, 128), 256, 0, stream>>>(OP, WT, conv_b,
                                                bn2_g, bn2_b, bn2_m, bn2_v, out);
}

// Round 16
// 260.117 us; speedup vs baseline: 1.0698x; 1.0698x over previous
//
#include <hip/hip_runtime.h>
#include <math.h>

// Problem constants (B,N,F_IN,HID,OUT,H,D) = (32,512,256,512,512,4,128)
#define BATCH 32
#define NNODE 512
#define FIN   256
#define HIDC  512
#define OUTC  512
#define NHEAD 4
#define HDIM  128
#define EPSV  1e-5f
#define ALPHA_LR 0.2f

typedef _Float16 half8 __attribute__((ext_vector_type(8)));
typedef _Float16 half4v __attribute__((ext_vector_type(4)));
typedef float floatx4 __attribute__((ext_vector_type(4)));

#define GLOBAL_TO_LDS16(g, l)                                                  \
  __builtin_amdgcn_global_load_lds(                                            \
      (const __attribute__((address_space(1))) void*)(g),                      \
      (__attribute__((address_space(3))) void*)(l), 16, 0, 0)

// ---------------------------------------------------------------------------
// Generic 128x128 split-fp16 MFMA GEMM core — BK=64: stage two 32-K
// sub-chunks (16 loads), ONE drain barrier, 96 MFMAs, one trailing barrier.
// Accumulation order identical (sub 0 then sub 1) -> bit-identical output.
// LDS 64 KB (2 blocks/CU at grid 512). Chunk-XOR bank swizzle (round-2).
// ---------------------------------------------------------------------------
__device__ __forceinline__ void split_gemm_acc(
    const _Float16* __restrict__ Ah, const _Float16* __restrict__ Al, int lda,
    const _Float16* __restrict__ Bh, const _Float16* __restrict__ Bl, int ldb,
    int K, int rowBase, int colBase,
    _Float16* sAh, _Float16* sAl, _Float16* sBh, _Float16* sBl,
    floatx4 acc[4][4], int tid) {
  const int lane = tid & 63, wave = tid >> 6;
  const int wr = (wave >> 1) * 64, wc = (wave & 1) * 64;
  const int fr = lane & 15, q = lane >> 4;
  const int r = tid >> 2;
  const int cks = (((tid & 3) ^ ((r >> 1) & 3))) * 8;  // swizzled source chunk
  const int qx = (q ^ ((fr >> 1) & 3)) * 8;            // swizzled read chunk
  for (int k0 = 0; k0 < K; k0 += 64) {
#pragma unroll
    for (int s = 0; s < 2; ++s) {
      const int kc = k0 + s * 32;
      const int o = s * 4096;
      GLOBAL_TO_LDS16(&Ah[(size_t)(rowBase + r) * lda + kc + cks], &sAh[o + tid * 8]);
      GLOBAL_TO_LDS16(&Ah[(size_t)(rowBase + r + 64) * lda + kc + cks], &sAh[o + 2048 + tid * 8]);
      GLOBAL_TO_LDS16(&Al[(size_t)(rowBase + r) * lda + kc + cks], &sAl[o + tid * 8]);
      GLOBAL_TO_LDS16(&Al[(size_t)(rowBase + r + 64) * lda + kc + cks], &sAl[o + 2048 + tid * 8]);
      GLOBAL_TO_LDS16(&Bh[(size_t)(colBase + r) * ldb + kc + cks], &sBh[o + tid * 8]);
      GLOBAL_TO_LDS16(&Bh[(size_t)(colBase + r + 64) * ldb + kc + cks], &sBh[o + 2048 + tid * 8]);
      GLOBAL_TO_LDS16(&Bl[(size_t)(colBase + r) * ldb + kc + cks], &sBl[o + tid * 8]);
      GLOBAL_TO_LDS16(&Bl[(size_t)(colBase + r + 64) * ldb + kc + cks], &sBl[o + 2048 + tid * 8]);
    }
    __syncthreads();
#pragma unroll
    for (int s = 0; s < 2; ++s) {
      const int o = s * 4096;
      half8 ah[4], al4[4], bh[4], bl4[4];
#pragma unroll
      for (int i = 0; i < 4; ++i) {
        ah[i]  = *(const half8*)&sAh[o + (wr + i * 16 + fr) * 32 + qx];
        al4[i] = *(const half8*)&sAl[o + (wr + i * 16 + fr) * 32 + qx];
      }
#pragma unroll
      for (int j = 0; j < 4; ++j) {
        bh[j]  = *(const half8*)&sBh[o + (wc + j * 16 + fr) * 32 + qx];
        bl4[j] = *(const half8*)&sBl[o + (wc + j * 16 + fr) * 32 + qx];
      }
#pragma unroll
      for (int i = 0; i < 4; ++i)
#pragma unroll
        for (int j = 0; j < 4; ++j) {
          acc[i][j] = __builtin_amdgcn_mfma_f32_16x16x32_f16(al4[i], bh[j], acc[i][j], 0, 0, 0);
          acc[i][j] = __builtin_amdgcn_mfma_f32_16x16x32_f16(ah[i], bl4[j], acc[i][j], 0, 0, 0);
          acc[i][j] = __builtin_amdgcn_mfma_f32_16x16x32_f16(ah[i], bh[j], acc[i][j], 0, 0, 0);
        }
    }
    __syncthreads();
  }
}

// ---------------------------------------------------------------------------
// Prep: splits + conv weight transform + OP halo zero.
// ---------------------------------------------------------------------------
__global__ __launch_bounds__(256) void k_prep(
    const float* __restrict__ adj, const float* __restrict__ gcw,
    const float* __restrict__ gatw, const float* __restrict__ cw,
    _Float16* __restrict__ ADJh, _Float16* __restrict__ ADJl,
    _Float16* __restrict__ GWh, _Float16* __restrict__ GWl,
    _Float16* __restrict__ GAh, _Float16* __restrict__ GAl,
    _Float16* __restrict__ WT, _Float16* __restrict__ OP) {
  const int i = blockIdx.x * 256 + threadIdx.x;
  if (i < 262144) {
    float v = adj[i];
    _Float16 h = (_Float16)v;
    ADJh[i] = h; ADJl[i] = (_Float16)(v - (float)h);
  } else if (i < 393216) {
    int j = i - 262144;
    int n = j >> 8, k = j & 255;
    float v = gcw[(size_t)k * HIDC + n];
    _Float16 h = (_Float16)v;
    GWh[j] = h; GWl[j] = (_Float16)(v - (float)h);
  } else if (i < 655360) {
    int j = i - 393216;
    float v = gatw[j];
    _Float16 h = (_Float16)v;
    GAh[j] = h; GAl[j] = (_Float16)(v - (float)h);
  } else if (i < 1441792) {
    int j = i - 655360;
    int n = j / 1536, kk = j - n * 1536;
    int tap = kk >> 9, ci = kk & 511;
    WT[j] = (_Float16)cw[(size_t)n * 1536 + ci * 3 + tap];
  } else if (i < 1474560) {
    int j = i - 1441792;
    int b = j >> 10, rs = (j >> 9) & 1, c = j & 511;
    OP[((size_t)b * 514 + rs * 513) * OUTC + c] = (_Float16)0.f;
  }
}

// ---------------------------------------------------------------------------
// x [b][m=512][f=256] fp32 -> transposed split XT[b][f][m] hi/lo fp16.
// LDS 64x64 tile transpose, pad 65 (conflict-free), coalesced both sides.
// ---------------------------------------------------------------------------
__global__ __launch_bounds__(256) void k_xsplit_t(const float* __restrict__ X,
                                                  _Float16* __restrict__ XTh,
                                                  _Float16* __restrict__ XTl) {
  __shared__ float sT[64][65];
  const int bt = blockIdx.x;          // 0..1023
  const int ft = bt & 3;              // 4 f-tiles of 64
  const int mt = (bt >> 2) & 7;       // 8 m-tiles of 64
  const int b  = bt >> 5;             // 32 batches
  const int tid = threadIdx.x;
  const int rr = tid >> 4, cc4 = (tid & 15) * 4;
#pragma unroll
  for (int it = 0; it < 4; ++it) {
    int m = rr + it * 16;
    float4 v = *(const float4*)&X[((size_t)(b * 512 + mt * 64 + m)) * 256 + ft * 64 + cc4];
    sT[m][cc4] = v.x; sT[m][cc4 + 1] = v.y; sT[m][cc4 + 2] = v.z; sT[m][cc4 + 3] = v.w;
  }
  __syncthreads();
#pragma unroll
  for (int it = 0; it < 4; ++it) {
    int f = rr + it * 16;
    half4v h, l;
#pragma unroll
    for (int e = 0; e < 4; ++e) {
      float v = sT[cc4 + e][f];
      _Float16 hh = (_Float16)v;
      h[e] = hh; l[e] = (_Float16)(v - (float)hh);
    }
    size_t base = ((size_t)b * 256 + ft * 64 + f) * 512 + mt * 64 + cc4;
    *(half4v*)&XTh[base] = h;
    *(half4v*)&XTl[base] = l;
  }
}

// ---------------------------------------------------------------------------
// AX = adj @ x per batch: C[bn, f] = sum_m adj[n,m] x[b,m,f].
// 128x64 tile, grid 512 = 2/CU. BK=64. LDS 48 KB. T1 XCD swizzle.
// ---------------------------------------------------------------------------
__global__ __launch_bounds__(256) void k_ax(
    const _Float16* __restrict__ ADJh, const _Float16* __restrict__ ADJl,
    const _Float16* __restrict__ XTh, const _Float16* __restrict__ XTl,
    _Float16* __restrict__ AXh, _Float16* __restrict__ AXl) {
  __shared__ _Float16 sAh[8192], sAl[8192], sBh[4096], sBl[4096];
  const int tid = threadIdx.x;
  const int lane = tid & 63, wave = tid >> 6;
  const int fr = lane & 15, q = lane >> 4;
  const int r = tid >> 2;
  const int cks = (((tid & 3) ^ ((r >> 1) & 3))) * 8;
  const int qx = (q ^ ((fr >> 1) & 3)) * 8;
  const int id = blockIdx.y * 4 + blockIdx.x;  // 0..511
  const int jj = id >> 3;
  const int rowBase = ((id & 7) * 16 + (jj >> 2)) * 128;  // global bn row
  const int colBase = (jj & 3) * 64;                      // f col
  const int b = rowBase >> 9;
  const int nrow = rowBase & 511;
  const _Float16* Bh = XTh + (size_t)b * FIN * NNODE;
  const _Float16* Bl = XTl + (size_t)b * FIN * NNODE;
  floatx4 acc[2][4] = {};
  for (int k0 = 0; k0 < NNODE; k0 += 64) {
#pragma unroll
    for (int s = 0; s < 2; ++s) {
      const int kc = k0 + s * 32;
      const int oA = s * 4096, oB = s * 2048;
      GLOBAL_TO_LDS16(&ADJh[(size_t)(nrow + r) * NNODE + kc + cks], &sAh[oA + tid * 8]);
      GLOBAL_TO_LDS16(&ADJh[(size_t)(nrow + r + 64) * NNODE + kc + cks], &sAh[oA + 2048 + tid * 8]);
      GLOBAL_TO_LDS16(&ADJl[(size_t)(nrow + r) * NNODE + kc + cks], &sAl[oA + tid * 8]);
      GLOBAL_TO_LDS16(&ADJl[(size_t)(nrow + r + 64) * NNODE + kc + cks], &sAl[oA + 2048 + tid * 8]);
      GLOBAL_TO_LDS16(&Bh[(size_t)(colBase + r) * NNODE + kc + cks], &sBh[oB + tid * 8]);
      GLOBAL_TO_LDS16(&Bl[(size_t)(colBase + r) * NNODE + kc + cks], &sBl[oB + tid * 8]);
    }
    __syncthreads();
#pragma unroll
    for (int s = 0; s < 2; ++s) {
      const int oA = s * 4096, oB = s * 2048;
      half8 ah[2], al4[2], bh[4], bl4[4];
#pragma unroll
      for (int i = 0; i < 2; ++i) {
        ah[i]  = *(const half8*)&sAh[oA + (wave * 32 + i * 16 + fr) * 32 + qx];
        al4[i] = *(const half8*)&sAl[oA + (wave * 32 + i * 16 + fr) * 32 + qx];
      }
#pragma unroll
      for (int j = 0; j < 4; ++j) {
        bh[j]  = *(const half8*)&sBh[oB + (j * 16 + fr) * 32 + qx];
        bl4[j] = *(const half8*)&sBl[oB + (j * 16 + fr) * 32 + qx];
      }
#pragma unroll
      for (int i = 0; i < 2; ++i)
#pragma unroll
        for (int j = 0; j < 4; ++j) {
          acc[i][j] = __builtin_amdgcn_mfma_f32_16x16x32_f16(al4[i], bh[j], acc[i][j], 0, 0, 0);
          acc[i][j] = __builtin_amdgcn_mfma_f32_16x16x32_f16(ah[i], bl4[j], acc[i][j], 0, 0, 0);
          acc[i][j] = __builtin_amdgcn_mfma_f32_16x16x32_f16(ah[i], bh[j], acc[i][j], 0, 0, 0);
        }
    }
    __syncthreads();
  }
#pragma unroll
  for (int i = 0; i < 2; ++i) {
    const int r0 = rowBase + wave * 32 + i * 16 + q * 4;
#pragma unroll
    for (int rg = 0; rg < 4; ++rg) {
      size_t base = (size_t)(r0 + rg) * FIN + colBase + fr;
#pragma unroll
      for (int j = 0; j < 4; ++j) {
        float v = acc[i][j][rg];
        _Float16 h = (_Float16)v;
        AXh[base + j * 16] = h;
        AXl[base + j * 16] = (_Float16)(v - (float)h);
      }
    }
  }
}

// ---------------------------------------------------------------------------
// g = relu(bn1(AX @ gc_w + gc_b)). M=16384, N=512, K=256. T1 XCD swizzle.
// ---------------------------------------------------------------------------
__global__ __launch_bounds__(256) void k_gcn2(
    const _Float16* __restrict__ AXh, const _Float16* __restrict__ AXl,
    const _Float16* __restrict__ GWh, const _Float16* __restrict__ GWl,
    const float* __restrict__ gcb, const float* __restrict__ g1,
    const float* __restrict__ b1, const float* __restrict__ m1,
    const float* __restrict__ v1,
    _Float16* __restrict__ Gh, _Float16* __restrict__ Gl) {
  __shared__ _Float16 sm[4][8192];   // BK=64 (64 KB)
  const int tid = threadIdx.x;
  const int id = blockIdx.y * 4 + blockIdx.x;  // 0..511
  const int jj = id >> 3;
  const int rowBase = ((id & 7) * 16 + (jj >> 2)) * 128;
  const int colBase = (jj & 3) * 128;
  floatx4 acc[4][4] = {};
  split_gemm_acc(AXh, AXl, FIN, GWh, GWl, FIN, FIN, rowBase, colBase,
                 sm[0], sm[1], sm[2], sm[3], acc, tid);
  const int lane = tid & 63, wave = tid >> 6;
  const int wr = (wave >> 1) * 64, wc = (wave & 1) * 64;
  const int fr = lane & 15, q = lane >> 4;
  float sc[4], of[4];
#pragma unroll
  for (int j = 0; j < 4; ++j) {
    int c = colBase + wc + j * 16 + fr;
    float s = g1[c] * rsqrtf(v1[c] + EPSV);
    sc[j] = s;
    of[j] = (gcb[c] - m1[c]) * s + b1[c];
  }
#pragma unroll
  for (int i = 0; i < 4; ++i) {
    const int r0 = rowBase + wr + i * 16 + q * 4;
#pragma unroll
    for (int rg = 0; rg < 4; ++rg) {
      size_t base = (size_t)(r0 + rg) * HIDC + colBase + wc + fr;
#pragma unroll
      for (int j = 0; j < 4; ++j) {
        float v = fmaxf(fmaf(acc[i][j][rg], sc[j], of[j]), 0.0f);
        _Float16 h = (_Float16)v;
        Gh[base + j * 16] = h;
        Gl[base + j * 16] = (_Float16)(v - (float)h);
      }
    }
  }
}

// ---------------------------------------------------------------------------
// hh = g @ gat_w^T : M=16384 N=512 K=512. Split output + fused transposed
// V write (HHT != nullptr). T1 XCD swizzle.
// ---------------------------------------------------------------------------
__global__ __launch_bounds__(256) void k_hh(
    const _Float16* __restrict__ Gh, const _Float16* __restrict__ Gl,
    const _Float16* __restrict__ GAh, const _Float16* __restrict__ GAl,
    _Float16* __restrict__ HHh, _Float16* __restrict__ HHl,
    _Float16* __restrict__ HHT) {
  __shared__ _Float16 sm[4][8192];   // BK=64 (64 KB)
  const int tid = threadIdx.x;
  const int id = blockIdx.y * 4 + blockIdx.x;  // 0..511
  const int jj = id >> 3;
  const int rowBase = ((id & 7) * 16 + (jj >> 2)) * 128;
  const int colBase = (jj & 3) * 128;
  floatx4 acc[4][4] = {};
  split_gemm_acc(Gh, Gl, HIDC, GAh, GAl, HIDC, HIDC, rowBase, colBase,
                 sm[0], sm[1], sm[2], sm[3], acc, tid);
  const int lane = tid & 63, wave = tid >> 6;
  const int wr = (wave >> 1) * 64, wc = (wave & 1) * 64;
  const int fr = lane & 15, q = lane >> 4;
#pragma unroll
  for (int i = 0; i < 4; ++i) {
    const int r0 = rowBase + wr + i * 16 + q * 4;
    const int node = r0 & 511;
    const int bbv = r0 >> 9;
#pragma unroll
    for (int j = 0; j < 4; ++j) {
      const int c = colBase + wc + j * 16 + fr;   // = h*128 + d
      half4v v4;
#pragma unroll
      for (int rg = 0; rg < 4; ++rg) {
        float v = acc[i][j][rg];
        _Float16 h = (_Float16)v;
        size_t base = (size_t)(r0 + rg) * OUTC + c;
        HHh[base] = h;
        HHl[base] = (_Float16)(v - (float)h);
        v4[rg] = h;
      }
      if (HHT)
        *(half4v*)&HHT[((size_t)(bbv * 4 + (c >> 7)) * 128 + (c & 127)) * 512 + node] = v4;
    }
  }
}

// ---------------------------------------------------------------------------
// k_vt fallback (small workspace): HHT[(bb*4+h)*128+d][node] = HHh[...].
// ---------------------------------------------------------------------------
__global__ __launch_bounds__(256) void k_vt(const _Float16* __restrict__ HHh,
                                            _Float16* __restrict__ HHT) {
  __shared__ _Float16 sT[128 * 132];
  const int bt = blockIdx.x;           // 0..511
  const int nt = bt & 3, g = bt >> 2;  // g = bb*4+h
  const int bb = g >> 2, h = g & 3;
  const int tid = threadIdx.x;
  const int rr = tid >> 4, cc = (tid & 15) * 8;
#pragma unroll
  for (int it = 0; it < 8; ++it) {
    int node = rr + it * 16;
    half8 v = *(const half8*)&HHh[((size_t)bb * 512 + nt * 128 + node) * 512 + h * 128 + cc];
#pragma unroll
    for (int e = 0; e < 8; ++e) sT[(cc + e) * 132 + node] = v[e];
  }
  __syncthreads();
#pragma unroll
  for (int it = 0; it < 8; ++it) {
    int d = rr + it * 16;
    half8 v;
#pragma unroll
    for (int e = 0; e < 8; ++e) v[e] = sT[d * 132 + cc + e];
    *(half8*)&HHT[((size_t)g * 128 + d) * 512 + nt * 128 + cc] = v;
  }
}

// ---------------------------------------------------------------------------
// Fused flash attention — round-7 proven form: round-2 schedule (4 plain
// barriers/kt, V overlays dead K, chunk-XOR swizzle) with 128 q-rows/block,
// grid 512. K/V fragments shared by the 2 m-tiles.
// ---------------------------------------------------------------------------
__global__ __launch_bounds__(256, 2) void k_attn(
    const _Float16* __restrict__ HHh, const _Float16* __restrict__ HHl,
    const _Float16* __restrict__ HHT, _Float16* __restrict__ OP) {
  __shared__ _Float16 sK[8][2048];   // tiles 0-3: K hi (k0=0..3), 4-7: K lo
  __shared__ _Float16 sP[128 * 68];  // [qrow][64 keys] stride 68
  _Float16* sV = &sK[0][0];          // V overlays dead K region after QK burst
  const int tid = threadIdx.x;
  const int lane = tid & 63, wave = tid >> 6;
  const int fr = lane & 15, q = lane >> 4;
  const int id = blockIdx.x;          // 0..511
  const int slot = id >> 3;           // 0..63
  const int g = (id & 7) + 8 * (slot >> 2);   // 0..127
  const int qBase = (slot & 3) * 128;
  const int bb = g >> 2, h = g & 3;
  const int w32 = wave * 32;
  const _Float16* Qh = HHh + (size_t)bb * NNODE * OUTC + h * HDIM;
  const _Float16* Ql = HHl + (size_t)bb * NNODE * OUTC + h * HDIM;
  const _Float16* VT = HHT + (size_t)g * HDIM * NNODE;  // [128 d][512 nodes]
  const int rk = tid >> 2;
  const int cks = (((tid & 3) ^ ((rk >> 1) & 3))) * 8;  // swizzled src chunk
  const int qx = (q ^ ((fr >> 1) & 3)) * 8;             // swizzled read chunk

  // Q fragments in registers: 2 m-tiles x 4 k0 (hi+lo), loaded once.
  half8 qh[2][4], ql[2][4];
#pragma unroll
  for (int m = 0; m < 2; ++m)
#pragma unroll
    for (int k0 = 0; k0 < 4; ++k0) {
      const size_t off = (size_t)(qBase + w32 + m * 16 + fr) * OUTC + k0 * 32 + q * 8;
      qh[m][k0] = *(const half8*)&Qh[off];
      ql[m][k0] = *(const half8*)&Ql[off];
    }

  floatx4 oacc[2][8] = {};
  float m_i[2][4], l_i[2][4];
#pragma unroll
  for (int m = 0; m < 2; ++m)
#pragma unroll
    for (int rg = 0; rg < 4; ++rg) { m_i[m][rg] = -1e30f; l_i[m][rg] = 0.f; }

  for (int kt = 0; kt < 8; ++kt) {
    const int ktb = kt * 64;
    // ---- stage whole 64-key K-tile (hi+lo, 32 KB, 8 sub-tiles) ----
#pragma unroll
    for (int t = 0; t < 4; ++t) {
      GLOBAL_TO_LDS16(&Qh[(size_t)(ktb + rk) * OUTC + t * 32 + cks], &sK[t][tid * 8]);
      GLOBAL_TO_LDS16(&Ql[(size_t)(ktb + rk) * OUTC + t * 32 + cks], &sK[4 + t][tid * 8]);
    }
    __syncthreads();
    // ---- S = Q @ K^T: 96-MFMA burst, K fragments shared across m ----
    floatx4 sacc[2][4] = {};
#pragma unroll
    for (int k0 = 0; k0 < 4; ++k0)
#pragma unroll
      for (int j = 0; j < 4; ++j) {
        half8 bh = *(const half8*)&sK[k0][(j * 16 + fr) * 32 + qx];
        half8 bl = *(const half8*)&sK[4 + k0][(j * 16 + fr) * 32 + qx];
#pragma unroll
        for (int m = 0; m < 2; ++m) {
          sacc[m][j] = __builtin_amdgcn_mfma_f32_16x16x32_f16(ql[m][k0], bh, sacc[m][j], 0, 0, 0);
          sacc[m][j] = __builtin_amdgcn_mfma_f32_16x16x32_f16(qh[m][k0], bl, sacc[m][j], 0, 0, 0);
          sacc[m][j] = __builtin_amdgcn_mfma_f32_16x16x32_f16(qh[m][k0], bh, sacc[m][j], 0, 0, 0);
        }
      }
    __syncthreads();   // sK fully consumed; safe to overlay with V
    // ---- LeakyReLU + online softmax (both m-tiles) ----
#pragma unroll
    for (int m = 0; m < 2; ++m) {
#pragma unroll
      for (int j = 0; j < 4; ++j)
#pragma unroll
        for (int rg = 0; rg < 4; ++rg) {
          float v = sacc[m][j][rg];
          sacc[m][j][rg] = v > 0.f ? v : ALPHA_LR * v;
        }
#pragma unroll
      for (int rg = 0; rg < 4; ++rg) {
        float mx = sacc[m][0][rg];
#pragma unroll
        for (int j = 1; j < 4; ++j) mx = fmaxf(mx, sacc[m][j][rg]);
        mx = fmaxf(mx, __shfl_xor(mx, 1));
        mx = fmaxf(mx, __shfl_xor(mx, 2));
        mx = fmaxf(mx, __shfl_xor(mx, 4));
        mx = fmaxf(mx, __shfl_xor(mx, 8));
        float mnew = fmaxf(m_i[m][rg], mx);
        float alpha = __expf(m_i[m][rg] - mnew);
        m_i[m][rg] = mnew;
        float sum = 0.f;
#pragma unroll
        for (int j = 0; j < 4; ++j) {
          float p = __expf(sacc[m][j][rg] - mnew);
          sacc[m][j][rg] = p;
          sum += p;
        }
        sum += __shfl_xor(sum, 1);
        sum += __shfl_xor(sum, 2);
        sum += __shfl_xor(sum, 4);
        sum += __shfl_xor(sum, 8);
        l_i[m][rg] = l_i[m][rg] * alpha + sum;
#pragma unroll
        for (int j = 0; j < 8; ++j) oacc[m][j][rg] *= alpha;   // ALL 8 d-cols
      }
    }
    // ---- stage V (2 ks-tiles from HHT, overlays sK) + write P ----
#pragma unroll
    for (int l = 0; l < 4; ++l)
      GLOBAL_TO_LDS16(&VT[(size_t)((l >> 1) * 64 + rk) * NNODE + ktb + (l & 1) * 32 + cks],
                      &sV[(l & 1) * 4096 + (l >> 1) * 2048 + tid * 8]);
#pragma unroll
    for (int m = 0; m < 2; ++m)
#pragma unroll
      for (int j = 0; j < 4; ++j)
#pragma unroll
        for (int rg = 0; rg < 4; ++rg)
          sP[(w32 + m * 16 + q * 4 + rg) * 68 + j * 16 + fr] = (_Float16)sacc[m][j][rg];
    __syncthreads();
    // ---- O += P @ V: 32-MFMA burst, V fragments shared across m ----
#pragma unroll
    for (int ks = 0; ks < 2; ++ks) {
      half8 pa0 = *(const half8*)&sP[(w32 + fr) * 68 + ks * 32 + q * 8];
      half8 pa1 = *(const half8*)&sP[(w32 + 16 + fr) * 68 + ks * 32 + q * 8];
#pragma unroll
      for (int j = 0; j < 8; ++j) {
        half8 bv = *(const half8*)&sV[ks * 4096 + (j * 16 + fr) * 32 + qx];
        oacc[0][j] = __builtin_amdgcn_mfma_f32_16x16x32_f16(pa0, bv, oacc[0][j], 0, 0, 0);
        oacc[1][j] = __builtin_amdgcn_mfma_f32_16x16x32_f16(pa1, bv, oacc[1][j], 0, 0, 0);
      }
    }
    __syncthreads();   // sV dead before next kt's K staging
  }
  // ---- normalize + write into padded conv input ----
#pragma unroll
  for (int m = 0; m < 2; ++m)
#pragma unroll
    for (int rg = 0; rg < 4; ++rg) {
      const float inv = 1.0f / l_i[m][rg];
      const int node = qBase + w32 + m * 16 + q * 4 + rg;
      size_t base = ((size_t)bb * 514 + 1 + node) * OUTC + h * HDIM + fr;
#pragma unroll
      for (int j = 0; j < 8; ++j)
        OP[base + j * 16] = (_Float16)(oacc[m][j][rg] * inv);
    }
}

// ---------------------------------------------------------------------------
// y = relu(bn2(conv1d(o)+conv_b)) via fp16 MFMA GEMM, XCD-swizzled.
// BK=64 (two 32-K sub-chunks per barrier pair), 32 MFMAs/step. LDS 32 KB.
// ---------------------------------------------------------------------------
__global__ __launch_bounds__(256) void k_conv_mfma(
    const _Float16* __restrict__ OP, const _Float16* __restrict__ WT,
    const float* __restrict__ cb, const float* __restrict__ g2,
    const float* __restrict__ b2, const float* __restrict__ m2,
    const float* __restrict__ v2, float* __restrict__ Y) {
  __shared__ _Float16 At[8192];
  __shared__ _Float16 Bt[8192];
  const int tid = threadIdx.x;
  const int lane = tid & 63, wave = tid >> 6;
  const int wr = (wave >> 1) * 64, wc = (wave & 1) * 64;
  const int id = blockIdx.y * 4 + blockIdx.x;
  const int jj = id >> 3;
  const int rowBase = ((id & 7) * 16 + (jj >> 2)) * 128;
  const int colBase = (jj & 3) * 128;
  const int b = rowBase >> 9;
  const int n0 = rowBase & 511;
  const int r = tid >> 2;
  const int cks = (((tid & 3) ^ ((r >> 1) & 3))) * 8;
  const int fr = lane & 15, q = lane >> 4;
  const int qx = (q ^ ((fr >> 1) & 3)) * 8;
  floatx4 acc[4][4] = {};
  for (int k0 = 0; k0 < 3 * OUTC; k0 += 64) {
#pragma unroll
    for (int s = 0; s < 2; ++s) {
      const int kc = k0 + s * 32;
      const int o = s * 4096;
      const int tap = kc >> 9;
      const int cib = kc & 511;
      const size_t abase = ((size_t)b * 514 + n0 + tap) * OUTC + cib + cks;
      GLOBAL_TO_LDS16(&OP[abase + (size_t)r * OUTC],        &At[o + tid * 8]);
      GLOBAL_TO_LDS16(&OP[abase + (size_t)(r + 64) * OUTC], &At[o + 2048 + tid * 8]);
      GLOBAL_TO_LDS16(&WT[(size_t)(colBase + r) * 1536 + kc + cks],      &Bt[o + tid * 8]);
      GLOBAL_TO_LDS16(&WT[(size_t)(colBase + r + 64) * 1536 + kc + cks], &Bt[o + 2048 + tid * 8]);
    }
    __syncthreads();
#pragma unroll
    for (int s = 0; s < 2; ++s) {
      const int o = s * 4096;
      half8 af[4], bf[4];
#pragma unroll
      for (int i = 0; i < 4; ++i)
        af[i] = *(const half8*)&At[o + (wr + i * 16 + fr) * 32 + qx];
#pragma unroll
      for (int j = 0; j < 4; ++j)
        bf[j] = *(const half8*)&Bt[o + (wc + j * 16 + fr) * 32 + qx];
#pragma unroll
      for (int i = 0; i < 4; ++i)
#pragma unroll
        for (int j = 0; j < 4; ++j)
          acc[i][j] = __builtin_amdgcn_mfma_f32_16x16x32_f16(af[i], bf[j], acc[i][j], 0, 0, 0);
    }
    __syncthreads();
  }
  float sc[4], of[4];
#pragma unroll
  for (int j = 0; j < 4; ++j) {
    int c = colBase + wc + j * 16 + fr;
    float s = g2[c] * rsqrtf(v2[c] + EPSV);
    sc[j] = s;
    of[j] = (cb[c] - m2[c]) * s + b2[c];
  }
#pragma unroll
  for (int i = 0; i < 4; ++i) {
    const int R0r = rowBase + wr + i * 16 + q * 4;
#pragma unroll
    for (int rg = 0; rg < 4; ++rg) {
      float* dst = &Y[(size_t)(R0r + rg) * OUTC + colBase + wc + fr];
#pragma unroll
      for (int j = 0; j < 4; ++j)
        dst[j * 16] = fmaxf(fmaf(acc[i][j][rg], sc[j], of[j]), 0.0f);
    }
  }
}

// ---------------------------------------------------------------------------
extern "C" void kernel_launch(void* const* d_in, const int* in_sizes, int n_in,
                              void* d_out, int out_size, void* d_ws, size_t ws_size,
                              hipStream_t stream) {
  const float* x     = (const float*)d_in[0];
  const float* adj   = (const float*)d_in[1];
  const float* gc_w  = (const float*)d_in[2];
  const float* gc_b  = (const float*)d_in[3];
  const float* bn1_g = (const float*)d_in[4];
  const float* bn1_b = (const float*)d_in[5];
  const float* bn1_m = (const float*)d_in[6];
  const float* bn1_v = (const float*)d_in[7];
  const float* gat_w = (const float*)d_in[8];
  const float* conv_w= (const float*)d_in[9];
  const float* conv_b= (const float*)d_in[10];
  const float* bn2_g = (const float*)d_in[11];
  const float* bn2_b = (const float*)d_in[12];
  const float* bn2_m = (const float*)d_in[13];
  const float* bn2_v = (const float*)d_in[14];
  float* out = (float*)d_out;

  char* ws = (char*)d_ws;
  _Float16* AXh = (_Float16*)(ws + 0);          // 8 MB [16384,256]
  _Float16* AXl = (_Float16*)(ws + 16777216);   // 8 MB
  _Float16* HHh = (_Float16*)(ws + 0);          // reuse after AX dead
  _Float16* HHl = (_Float16*)(ws + 16777216);
  _Float16* XTh = (_Float16*)(ws + 33554432);   // 8 MB [32][256][512]
  _Float16* XTl = (_Float16*)(ws + 41943040);   // 8 MB
  _Float16* Gh  = (_Float16*)(ws + 33554432);   // reuse after XT dead
  _Float16* Gl  = (_Float16*)(ws + 50331648);
  _Float16* OP  = (_Float16*)(ws + 67108864);
  _Float16* WT  = (_Float16*)(ws + 83951616);
  _Float16* ADJh= (_Float16*)(ws + 85524480);
  _Float16* ADJl= (_Float16*)(ws + 86048768);
  _Float16* GWh = (_Float16*)(ws + 86573056);
  _Float16* GWl = (_Float16*)(ws + 86835200);
  _Float16* GAh = (_Float16*)(ws + 87097344);
  _Float16* GAl = (_Float16*)(ws + 87621632);

  // HHT placement: fused path needs a region NOT aliasing Gh/Gl (k_hh reads
  // G while writing HHT). If the workspace has room past the static
  // allocations, put HHT there and fuse; else fall back to separate k_vt.
  const bool fused = ws_size >= (size_t)(88145920 + 16777216);
  _Float16* HHT = fused ? (_Float16*)(ws + 88145920)
                        : (_Float16*)(ws + 33554432);

  k_prep<<<5760, 256, 0, stream>>>(adj, gc_w, gat_w, conv_w,
                                   ADJh, ADJl, GWh, GWl, GAh, GAl, WT, OP);
  k_xsplit_t<<<1024, 256, 0, stream>>>(x, XTh, XTl);
  k_ax<<<dim3(4, 128), 256, 0, stream>>>(ADJh, ADJl, XTh, XTl, AXh, AXl);
  k_gcn2<<<dim3(4, 128), 256, 0, stream>>>(AXh, AXl, GWh, GWl, gc_b,
                                           bn1_g, bn1_b, bn1_m, bn1_v, Gh, Gl);
  if (fused) {
    k_hh<<<dim3(4, 128), 256, 0, stream>>>(Gh, Gl, GAh, GAl, HHh, HHl, HHT);
  } else {
    k_hh<<<dim3(4, 128), 256, 0, stream>>>(Gh, Gl, GAh, GAl, HHh, HHl,
                                           (_Float16*)nullptr);
    k_vt<<<512, 256, 0, stream>>>(HHh, HHT);
  }
  k_attn<<<512, 256, 0, stream>>>(HHh, HHl, HHT, OP);
  k_conv_mfma<<<dim3(4, 128), 256, 0, stream>>>(OP, WT, conv_b,
                                                bn2_g, bn2_b, bn2_m, bn2_v, out);
}

// Round 17
// 245.042 us; speedup vs baseline: 1.1356x; 1.0615x over previous
//
#include <hip/hip_runtime.h>
#include <math.h>

// Problem constants (B,N,F_IN,HID,OUT,H,D) = (32,512,256,512,512,4,128)
#define BATCH 32
#define NNODE 512
#define FIN   256
#define HIDC  512
#define OUTC  512
#define NHEAD 4
#define HDIM  128
#define EPSV  1e-5f
#define ALPHA_LR 0.2f

typedef _Float16 half8 __attribute__((ext_vector_type(8)));
typedef _Float16 half4v __attribute__((ext_vector_type(4)));
typedef float floatx4 __attribute__((ext_vector_type(4)));

#define GLOBAL_TO_LDS16(g, l)                                                  \
  __builtin_amdgcn_global_load_lds(                                            \
      (const __attribute__((address_space(1))) void*)(g),                      \
      (__attribute__((address_space(3))) void*)(l), 16, 0, 0)

// ---------------------------------------------------------------------------
// Generic 128x128 split-fp16 MFMA GEMM core — BK=64 (round-10 proven form).
// Chunk-XOR bank swizzle (round-2). Bit-identical accumulation order.
// ---------------------------------------------------------------------------
__device__ __forceinline__ void split_gemm_acc(
    const _Float16* __restrict__ Ah, const _Float16* __restrict__ Al, int lda,
    const _Float16* __restrict__ Bh, const _Float16* __restrict__ Bl, int ldb,
    int K, int rowBase, int colBase,
    _Float16* sAh, _Float16* sAl, _Float16* sBh, _Float16* sBl,
    floatx4 acc[4][4], int tid) {
  const int lane = tid & 63, wave = tid >> 6;
  const int wr = (wave >> 1) * 64, wc = (wave & 1) * 64;
  const int fr = lane & 15, q = lane >> 4;
  const int r = tid >> 2;
  const int cks = (((tid & 3) ^ ((r >> 1) & 3))) * 8;  // swizzled source chunk
  const int qx = (q ^ ((fr >> 1) & 3)) * 8;            // swizzled read chunk
  for (int k0 = 0; k0 < K; k0 += 64) {
#pragma unroll
    for (int s = 0; s < 2; ++s) {
      const int kc = k0 + s * 32;
      const int o = s * 4096;
      GLOBAL_TO_LDS16(&Ah[(size_t)(rowBase + r) * lda + kc + cks], &sAh[o + tid * 8]);
      GLOBAL_TO_LDS16(&Ah[(size_t)(rowBase + r + 64) * lda + kc + cks], &sAh[o + 2048 + tid * 8]);
      GLOBAL_TO_LDS16(&Al[(size_t)(rowBase + r) * lda + kc + cks], &sAl[o + tid * 8]);
      GLOBAL_TO_LDS16(&Al[(size_t)(rowBase + r + 64) * lda + kc + cks], &sAl[o + 2048 + tid * 8]);
      GLOBAL_TO_LDS16(&Bh[(size_t)(colBase + r) * ldb + kc + cks], &sBh[o + tid * 8]);
      GLOBAL_TO_LDS16(&Bh[(size_t)(colBase + r + 64) * ldb + kc + cks], &sBh[o + 2048 + tid * 8]);
      GLOBAL_TO_LDS16(&Bl[(size_t)(colBase + r) * ldb + kc + cks], &sBl[o + tid * 8]);
      GLOBAL_TO_LDS16(&Bl[(size_t)(colBase + r + 64) * ldb + kc + cks], &sBl[o + 2048 + tid * 8]);
    }
    __syncthreads();
#pragma unroll
    for (int s = 0; s < 2; ++s) {
      const int o = s * 4096;
      half8 ah[4], al4[4], bh[4], bl4[4];
#pragma unroll
      for (int i = 0; i < 4; ++i) {
        ah[i]  = *(const half8*)&sAh[o + (wr + i * 16 + fr) * 32 + qx];
        al4[i] = *(const half8*)&sAl[o + (wr + i * 16 + fr) * 32 + qx];
      }
#pragma unroll
      for (int j = 0; j < 4; ++j) {
        bh[j]  = *(const half8*)&sBh[o + (wc + j * 16 + fr) * 32 + qx];
        bl4[j] = *(const half8*)&sBl[o + (wc + j * 16 + fr) * 32 + qx];
      }
#pragma unroll
      for (int i = 0; i < 4; ++i)
#pragma unroll
        for (int j = 0; j < 4; ++j) {
          acc[i][j] = __builtin_amdgcn_mfma_f32_16x16x32_f16(al4[i], bh[j], acc[i][j], 0, 0, 0);
          acc[i][j] = __builtin_amdgcn_mfma_f32_16x16x32_f16(ah[i], bl4[j], acc[i][j], 0, 0, 0);
          acc[i][j] = __builtin_amdgcn_mfma_f32_16x16x32_f16(ah[i], bh[j], acc[i][j], 0, 0, 0);
        }
    }
    __syncthreads();
  }
}

// ---------------------------------------------------------------------------
// Prep: splits + conv weight transform + OP halo zero.
// ---------------------------------------------------------------------------
__global__ __launch_bounds__(256) void k_prep(
    const float* __restrict__ adj, const float* __restrict__ gcw,
    const float* __restrict__ gatw, const float* __restrict__ cw,
    _Float16* __restrict__ ADJh, _Float16* __restrict__ ADJl,
    _Float16* __restrict__ GWh, _Float16* __restrict__ GWl,
    _Float16* __restrict__ GAh, _Float16* __restrict__ GAl,
    _Float16* __restrict__ WT, _Float16* __restrict__ OP) {
  const int i = blockIdx.x * 256 + threadIdx.x;
  if (i < 262144) {
    float v = adj[i];
    _Float16 h = (_Float16)v;
    ADJh[i] = h; ADJl[i] = (_Float16)(v - (float)h);
  } else if (i < 393216) {
    int j = i - 262144;
    int n = j >> 8, k = j & 255;
    float v = gcw[(size_t)k * HIDC + n];
    _Float16 h = (_Float16)v;
    GWh[j] = h; GWl[j] = (_Float16)(v - (float)h);
  } else if (i < 655360) {
    int j = i - 393216;
    float v = gatw[j];
    _Float16 h = (_Float16)v;
    GAh[j] = h; GAl[j] = (_Float16)(v - (float)h);
  } else if (i < 1441792) {
    int j = i - 655360;
    int n = j / 1536, kk = j - n * 1536;
    int tap = kk >> 9, ci = kk & 511;
    WT[j] = (_Float16)cw[(size_t)n * 1536 + ci * 3 + tap];
  } else if (i < 1474560) {
    int j = i - 1441792;
    int b = j >> 10, rs = (j >> 9) & 1, c = j & 511;
    OP[((size_t)b * 514 + rs * 513) * OUTC + c] = (_Float16)0.f;
  }
}

// ---------------------------------------------------------------------------
// x [b][m=512][f=256] fp32 -> transposed split XT[b][f][m] hi/lo fp16.
// ---------------------------------------------------------------------------
__global__ __launch_bounds__(256) void k_xsplit_t(const float* __restrict__ X,
                                                  _Float16* __restrict__ XTh,
                                                  _Float16* __restrict__ XTl) {
  __shared__ float sT[64][65];
  const int bt = blockIdx.x;          // 0..1023
  const int ft = bt & 3;              // 4 f-tiles of 64
  const int mt = (bt >> 2) & 7;       // 8 m-tiles of 64
  const int b  = bt >> 5;             // 32 batches
  const int tid = threadIdx.x;
  const int rr = tid >> 4, cc4 = (tid & 15) * 4;
#pragma unroll
  for (int it = 0; it < 4; ++it) {
    int m = rr + it * 16;
    float4 v = *(const float4*)&X[((size_t)(b * 512 + mt * 64 + m)) * 256 + ft * 64 + cc4];
    sT[m][cc4] = v.x; sT[m][cc4 + 1] = v.y; sT[m][cc4 + 2] = v.z; sT[m][cc4 + 3] = v.w;
  }
  __syncthreads();
#pragma unroll
  for (int it = 0; it < 4; ++it) {
    int f = rr + it * 16;
    half4v h, l;
#pragma unroll
    for (int e = 0; e < 4; ++e) {
      float v = sT[cc4 + e][f];
      _Float16 hh = (_Float16)v;
      h[e] = hh; l[e] = (_Float16)(v - (float)hh);
    }
    size_t base = ((size_t)b * 256 + ft * 64 + f) * 512 + mt * 64 + cc4;
    *(half4v*)&XTh[base] = h;
    *(half4v*)&XTl[base] = l;
  }
}

// ---------------------------------------------------------------------------
// AX = adj @ x per batch. 128x64 tile, grid 512 = 2/CU. BK=64. T1 swizzle.
// ---------------------------------------------------------------------------
__global__ __launch_bounds__(256) void k_ax(
    const _Float16* __restrict__ ADJh, const _Float16* __restrict__ ADJl,
    const _Float16* __restrict__ XTh, const _Float16* __restrict__ XTl,
    _Float16* __restrict__ AXh, _Float16* __restrict__ AXl) {
  __shared__ _Float16 sAh[8192], sAl[8192], sBh[4096], sBl[4096];
  const int tid = threadIdx.x;
  const int lane = tid & 63, wave = tid >> 6;
  const int fr = lane & 15, q = lane >> 4;
  const int r = tid >> 2;
  const int cks = (((tid & 3) ^ ((r >> 1) & 3))) * 8;
  const int qx = (q ^ ((fr >> 1) & 3)) * 8;
  const int id = blockIdx.y * 4 + blockIdx.x;  // 0..511
  const int jj = id >> 3;
  const int rowBase = ((id & 7) * 16 + (jj >> 2)) * 128;  // global bn row
  const int colBase = (jj & 3) * 64;                      // f col
  const int b = rowBase >> 9;
  const int nrow = rowBase & 511;
  const _Float16* Bh = XTh + (size_t)b * FIN * NNODE;
  const _Float16* Bl = XTl + (size_t)b * FIN * NNODE;
  floatx4 acc[2][4] = {};
  for (int k0 = 0; k0 < NNODE; k0 += 64) {
#pragma unroll
    for (int s = 0; s < 2; ++s) {
      const int kc = k0 + s * 32;
      const int oA = s * 4096, oB = s * 2048;
      GLOBAL_TO_LDS16(&ADJh[(size_t)(nrow + r) * NNODE + kc + cks], &sAh[oA + tid * 8]);
      GLOBAL_TO_LDS16(&ADJh[(size_t)(nrow + r + 64) * NNODE + kc + cks], &sAh[oA + 2048 + tid * 8]);
      GLOBAL_TO_LDS16(&ADJl[(size_t)(nrow + r) * NNODE + kc + cks], &sAl[oA + tid * 8]);
      GLOBAL_TO_LDS16(&ADJl[(size_t)(nrow + r + 64) * NNODE + kc + cks], &sAl[oA + 2048 + tid * 8]);
      GLOBAL_TO_LDS16(&Bh[(size_t)(colBase + r) * NNODE + kc + cks], &sBh[oB + tid * 8]);
      GLOBAL_TO_LDS16(&Bl[(size_t)(colBase + r) * NNODE + kc + cks], &sBl[oB + tid * 8]);
    }
    __syncthreads();
#pragma unroll
    for (int s = 0; s < 2; ++s) {
      const int oA = s * 4096, oB = s * 2048;
      half8 ah[2], al4[2], bh[4], bl4[4];
#pragma unroll
      for (int i = 0; i < 2; ++i) {
        ah[i]  = *(const half8*)&sAh[oA + (wave * 32 + i * 16 + fr) * 32 + qx];
        al4[i] = *(const half8*)&sAl[oA + (wave * 32 + i * 16 + fr) * 32 + qx];
      }
#pragma unroll
      for (int j = 0; j < 4; ++j) {
        bh[j]  = *(const half8*)&sBh[oB + (j * 16 + fr) * 32 + qx];
        bl4[j] = *(const half8*)&sBl[oB + (j * 16 + fr) * 32 + qx];
      }
#pragma unroll
      for (int i = 0; i < 2; ++i)
#pragma unroll
        for (int j = 0; j < 4; ++j) {
          acc[i][j] = __builtin_amdgcn_mfma_f32_16x16x32_f16(al4[i], bh[j], acc[i][j], 0, 0, 0);
          acc[i][j] = __builtin_amdgcn_mfma_f32_16x16x32_f16(ah[i], bl4[j], acc[i][j], 0, 0, 0);
          acc[i][j] = __builtin_amdgcn_mfma_f32_16x16x32_f16(ah[i], bh[j], acc[i][j], 0, 0, 0);
        }
    }
    __syncthreads();
  }
#pragma unroll
  for (int i = 0; i < 2; ++i) {
    const int r0 = rowBase + wave * 32 + i * 16 + q * 4;
#pragma unroll
    for (int rg = 0; rg < 4; ++rg) {
      size_t base = (size_t)(r0 + rg) * FIN + colBase + fr;
#pragma unroll
      for (int j = 0; j < 4; ++j) {
        float v = acc[i][j][rg];
        _Float16 h = (_Float16)v;
        AXh[base + j * 16] = h;
        AXl[base + j * 16] = (_Float16)(v - (float)h);
      }
    }
  }
}

// ---------------------------------------------------------------------------
// g = relu(bn1(AX @ gc_w + gc_b)). T1 XCD swizzle.
// ---------------------------------------------------------------------------
__global__ __launch_bounds__(256) void k_gcn2(
    const _Float16* __restrict__ AXh, const _Float16* __restrict__ AXl,
    const _Float16* __restrict__ GWh, const _Float16* __restrict__ GWl,
    const float* __restrict__ gcb, const float* __restrict__ g1,
    const float* __restrict__ b1, const float* __restrict__ m1,
    const float* __restrict__ v1,
    _Float16* __restrict__ Gh, _Float16* __restrict__ Gl) {
  __shared__ _Float16 sm[4][8192];   // BK=64 (64 KB)
  const int tid = threadIdx.x;
  const int id = blockIdx.y * 4 + blockIdx.x;  // 0..511
  const int jj = id >> 3;
  const int rowBase = ((id & 7) * 16 + (jj >> 2)) * 128;
  const int colBase = (jj & 3) * 128;
  floatx4 acc[4][4] = {};
  split_gemm_acc(AXh, AXl, FIN, GWh, GWl, FIN, FIN, rowBase, colBase,
                 sm[0], sm[1], sm[2], sm[3], acc, tid);
  const int lane = tid & 63, wave = tid >> 6;
  const int wr = (wave >> 1) * 64, wc = (wave & 1) * 64;
  const int fr = lane & 15, q = lane >> 4;
  float sc[4], of[4];
#pragma unroll
  for (int j = 0; j < 4; ++j) {
    int c = colBase + wc + j * 16 + fr;
    float s = g1[c] * rsqrtf(v1[c] + EPSV);
    sc[j] = s;
    of[j] = (gcb[c] - m1[c]) * s + b1[c];
  }
#pragma unroll
  for (int i = 0; i < 4; ++i) {
    const int r0 = rowBase + wr + i * 16 + q * 4;
#pragma unroll
    for (int rg = 0; rg < 4; ++rg) {
      size_t base = (size_t)(r0 + rg) * HIDC + colBase + wc + fr;
#pragma unroll
      for (int j = 0; j < 4; ++j) {
        float v = fmaxf(fmaf(acc[i][j][rg], sc[j], of[j]), 0.0f);
        _Float16 h = (_Float16)v;
        Gh[base + j * 16] = h;
        Gl[base + j * 16] = (_Float16)(v - (float)h);
      }
    }
  }
}

// ---------------------------------------------------------------------------
// hh = g @ gat_w^T. Writes HHh (hi only — lo no longer consumed) + fused
// transposed V write (HHT != nullptr). T1 XCD swizzle.
// ---------------------------------------------------------------------------
__global__ __launch_bounds__(256) void k_hh(
    const _Float16* __restrict__ Gh, const _Float16* __restrict__ Gl,
    const _Float16* __restrict__ GAh, const _Float16* __restrict__ GAl,
    _Float16* __restrict__ HHh, _Float16* __restrict__ HHT) {
  __shared__ _Float16 sm[4][8192];   // BK=64 (64 KB)
  const int tid = threadIdx.x;
  const int id = blockIdx.y * 4 + blockIdx.x;  // 0..511
  const int jj = id >> 3;
  const int rowBase = ((id & 7) * 16 + (jj >> 2)) * 128;
  const int colBase = (jj & 3) * 128;
  floatx4 acc[4][4] = {};
  split_gemm_acc(Gh, Gl, HIDC, GAh, GAl, HIDC, HIDC, rowBase, colBase,
                 sm[0], sm[1], sm[2], sm[3], acc, tid);
  const int lane = tid & 63, wave = tid >> 6;
  const int wr = (wave >> 1) * 64, wc = (wave & 1) * 64;
  const int fr = lane & 15, q = lane >> 4;
#pragma unroll
  for (int i = 0; i < 4; ++i) {
    const int r0 = rowBase + wr + i * 16 + q * 4;
    const int node = r0 & 511;
    const int bbv = r0 >> 9;
#pragma unroll
    for (int j = 0; j < 4; ++j) {
      const int c = colBase + wc + j * 16 + fr;   // = h*128 + d
      half4v v4;
#pragma unroll
      for (int rg = 0; rg < 4; ++rg) {
        float v = acc[i][j][rg];
        _Float16 h = (_Float16)v;
        HHh[(size_t)(r0 + rg) * OUTC + c] = h;
        v4[rg] = h;
      }
      if (HHT)
        *(half4v*)&HHT[((size_t)(bbv * 4 + (c >> 7)) * 128 + (c & 127)) * 512 + node] = v4;
    }
  }
}

// ---------------------------------------------------------------------------
// k_vt fallback (small workspace): HHT[(bb*4+h)*128+d][node] = HHh[...].
// ---------------------------------------------------------------------------
__global__ __launch_bounds__(256) void k_vt(const _Float16* __restrict__ HHh,
                                            _Float16* __restrict__ HHT) {
  __shared__ _Float16 sT[128 * 132];
  const int bt = blockIdx.x;           // 0..511
  const int nt = bt & 3, g = bt >> 2;  // g = bb*4+h
  const int bb = g >> 2, h = g & 3;
  const int tid = threadIdx.x;
  const int rr = tid >> 4, cc = (tid & 15) * 8;
#pragma unroll
  for (int it = 0; it < 8; ++it) {
    int node = rr + it * 16;
    half8 v = *(const half8*)&HHh[((size_t)bb * 512 + nt * 128 + node) * 512 + h * 128 + cc];
#pragma unroll
    for (int e = 0; e < 8; ++e) sT[(cc + e) * 132 + node] = v[e];
  }
  __syncthreads();
#pragma unroll
  for (int it = 0; it < 8; ++it) {
    int d = rr + it * 16;
    half8 v;
#pragma unroll
    for (int e = 0; e < 8; ++e) v[e] = sT[d * 132 + cc + e];
    *(half8*)&HHT[((size_t)g * 128 + d) * 512 + nt * 128 + cc] = v;
  }
}

// ---------------------------------------------------------------------------
// Fused flash attention — round-7/16 structure with HI-ONLY QK^T:
// logits use fp16 hi halves of Q and K only (error ~3e-4 relative, well
// inside the output bf16 quantization floor). QK burst 96 -> 32 MFMAs/kt;
// K staging 8 -> 4 loads/kt; sK 16 KB (V overlays it exactly). Softmax, P,
// PV unchanged. LDS 33792 B, grid 512 = 2/CU.
// ---------------------------------------------------------------------------
__global__ __launch_bounds__(256, 2) void k_attn(
    const _Float16* __restrict__ HHh,
    const _Float16* __restrict__ HHT, _Float16* __restrict__ OP) {
  __shared__ _Float16 sK[4][2048];   // K hi tiles (16 KB); V overlays after QK
  __shared__ _Float16 sP[128 * 68];  // [qrow][64 keys] stride 68
  _Float16* sV = &sK[0][0];
  const int tid = threadIdx.x;
  const int lane = tid & 63, wave = tid >> 6;
  const int fr = lane & 15, q = lane >> 4;
  const int id = blockIdx.x;          // 0..511
  const int slot = id >> 3;           // 0..63
  const int g = (id & 7) + 8 * (slot >> 2);   // 0..127
  const int qBase = (slot & 3) * 128;
  const int bb = g >> 2, h = g & 3;
  const int w32 = wave * 32;
  const _Float16* Qh = HHh + (size_t)bb * NNODE * OUTC + h * HDIM;
  const _Float16* VT = HHT + (size_t)g * HDIM * NNODE;  // [128 d][512 nodes]
  const int rk = tid >> 2;
  const int cks = (((tid & 3) ^ ((rk >> 1) & 3))) * 8;  // swizzled src chunk
  const int qx = (q ^ ((fr >> 1) & 3)) * 8;             // swizzled read chunk

  // Q fragments (hi only): 2 m-tiles x 4 k0, loaded once.
  half8 qh[2][4];
#pragma unroll
  for (int m = 0; m < 2; ++m)
#pragma unroll
    for (int k0 = 0; k0 < 4; ++k0) {
      const size_t off = (size_t)(qBase + w32 + m * 16 + fr) * OUTC + k0 * 32 + q * 8;
      qh[m][k0] = *(const half8*)&Qh[off];
    }

  floatx4 oacc[2][8] = {};
  float m_i[2][4], l_i[2][4];
#pragma unroll
  for (int m = 0; m < 2; ++m)
#pragma unroll
    for (int rg = 0; rg < 4; ++rg) { m_i[m][rg] = -1e30f; l_i[m][rg] = 0.f; }

  for (int kt = 0; kt < 8; ++kt) {
    const int ktb = kt * 64;
    // ---- stage 64-key K-tile (hi only, 16 KB, 4 sub-tiles) ----
#pragma unroll
    for (int t = 0; t < 4; ++t)
      GLOBAL_TO_LDS16(&Qh[(size_t)(ktb + rk) * OUTC + t * 32 + cks], &sK[t][tid * 8]);
    __syncthreads();
    // ---- S = Qhi @ Khi^T: 32-MFMA burst, K fragments shared across m ----
    floatx4 sacc[2][4] = {};
#pragma unroll
    for (int k0 = 0; k0 < 4; ++k0)
#pragma unroll
      for (int j = 0; j < 4; ++j) {
        half8 bh = *(const half8*)&sK[k0][(j * 16 + fr) * 32 + qx];
#pragma unroll
        for (int m = 0; m < 2; ++m)
          sacc[m][j] = __builtin_amdgcn_mfma_f32_16x16x32_f16(qh[m][k0], bh, sacc[m][j], 0, 0, 0);
      }
    __syncthreads();   // sK fully consumed; safe to overlay with V
    // ---- LeakyReLU + online softmax (both m-tiles) ----
#pragma unroll
    for (int m = 0; m < 2; ++m) {
#pragma unroll
      for (int j = 0; j < 4; ++j)
#pragma unroll
        for (int rg = 0; rg < 4; ++rg) {
          float v = sacc[m][j][rg];
          sacc[m][j][rg] = v > 0.f ? v : ALPHA_LR * v;
        }
#pragma unroll
      for (int rg = 0; rg < 4; ++rg) {
        float mx = sacc[m][0][rg];
#pragma unroll
        for (int j = 1; j < 4; ++j) mx = fmaxf(mx, sacc[m][j][rg]);
        mx = fmaxf(mx, __shfl_xor(mx, 1));
        mx = fmaxf(mx, __shfl_xor(mx, 2));
        mx = fmaxf(mx, __shfl_xor(mx, 4));
        mx = fmaxf(mx, __shfl_xor(mx, 8));
        float mnew = fmaxf(m_i[m][rg], mx);
        float alpha = __expf(m_i[m][rg] - mnew);
        m_i[m][rg] = mnew;
        float sum = 0.f;
#pragma unroll
        for (int j = 0; j < 4; ++j) {
          float p = __expf(sacc[m][j][rg] - mnew);
          sacc[m][j][rg] = p;
          sum += p;
        }
        sum += __shfl_xor(sum, 1);
        sum += __shfl_xor(sum, 2);
        sum += __shfl_xor(sum, 4);
        sum += __shfl_xor(sum, 8);
        l_i[m][rg] = l_i[m][rg] * alpha + sum;
#pragma unroll
        for (int j = 0; j < 8; ++j) oacc[m][j][rg] *= alpha;   // ALL 8 d-cols
      }
    }
    // ---- stage V (2 ks-tiles from HHT, overlays sK) + write P ----
#pragma unroll
    for (int l = 0; l < 4; ++l)
      GLOBAL_TO_LDS16(&VT[(size_t)((l >> 1) * 64 + rk) * NNODE + ktb + (l & 1) * 32 + cks],
                      &sV[(l & 1) * 4096 + (l >> 1) * 2048 + tid * 8]);
#pragma unroll
    for (int m = 0; m < 2; ++m)
#pragma unroll
      for (int j = 0; j < 4; ++j)
#pragma unroll
        for (int rg = 0; rg < 4; ++rg)
          sP[(w32 + m * 16 + q * 4 + rg) * 68 + j * 16 + fr] = (_Float16)sacc[m][j][rg];
    __syncthreads();
    // ---- O += P @ V: 32-MFMA burst, V fragments shared across m ----
#pragma unroll
    for (int ks = 0; ks < 2; ++ks) {
      half8 pa0 = *(const half8*)&sP[(w32 + fr) * 68 + ks * 32 + q * 8];
      half8 pa1 = *(const half8*)&sP[(w32 + 16 + fr) * 68 + ks * 32 + q * 8];
#pragma unroll
      for (int j = 0; j < 8; ++j) {
        half8 bv = *(const half8*)&sV[ks * 4096 + (j * 16 + fr) * 32 + qx];
        oacc[0][j] = __builtin_amdgcn_mfma_f32_16x16x32_f16(pa0, bv, oacc[0][j], 0, 0, 0);
        oacc[1][j] = __builtin_amdgcn_mfma_f32_16x16x32_f16(pa1, bv, oacc[1][j], 0, 0, 0);
      }
    }
    __syncthreads();   // sV dead before next kt's K staging
  }
  // ---- normalize + write into padded conv input ----
#pragma unroll
  for (int m = 0; m < 2; ++m)
#pragma unroll
    for (int rg = 0; rg < 4; ++rg) {
      const float inv = 1.0f / l_i[m][rg];
      const int node = qBase + w32 + m * 16 + q * 4 + rg;
      size_t base = ((size_t)bb * 514 + 1 + node) * OUTC + h * HDIM + fr;
#pragma unroll
      for (int j = 0; j < 8; ++j)
        OP[base + j * 16] = (_Float16)(oacc[m][j][rg] * inv);
    }
}

// ---------------------------------------------------------------------------
// y = relu(bn2(conv1d(o)+conv_b)) via fp16 MFMA GEMM, XCD-swizzled. BK=64.
// ---------------------------------------------------------------------------
__global__ __launch_bounds__(256) void k_conv_mfma(
    const _Float16* __restrict__ OP, const _Float16* __restrict__ WT,
    const float* __restrict__ cb, const float* __restrict__ g2,
    const float* __restrict__ b2, const float* __restrict__ m2,
    const float* __restrict__ v2, float* __restrict__ Y) {
  __shared__ _Float16 At[8192];
  __shared__ _Float16 Bt[8192];
  const int tid = threadIdx.x;
  const int lane = tid & 63, wave = tid >> 6;
  const int wr = (wave >> 1) * 64, wc = (wave & 1) * 64;
  const int id = blockIdx.y * 4 + blockIdx.x;
  const int jj = id >> 3;
  const int rowBase = ((id & 7) * 16 + (jj >> 2)) * 128;
  const int colBase = (jj & 3) * 128;
  const int b = rowBase >> 9;
  const int n0 = rowBase & 511;
  const int r = tid >> 2;
  const int cks = (((tid & 3) ^ ((r >> 1) & 3))) * 8;
  const int fr = lane & 15, q = lane >> 4;
  const int qx = (q ^ ((fr >> 1) & 3)) * 8;
  floatx4 acc[4][4] = {};
  for (int k0 = 0; k0 < 3 * OUTC; k0 += 64) {
#pragma unroll
    for (int s = 0; s < 2; ++s) {
      const int kc = k0 + s * 32;
      const int o = s * 4096;
      const int tap = kc >> 9;
      const int cib = kc & 511;
      const size_t abase = ((size_t)b * 514 + n0 + tap) * OUTC + cib + cks;
      GLOBAL_TO_LDS16(&OP[abase + (size_t)r * OUTC],        &At[o + tid * 8]);
      GLOBAL_TO_LDS16(&OP[abase + (size_t)(r + 64) * OUTC], &At[o + 2048 + tid * 8]);
      GLOBAL_TO_LDS16(&WT[(size_t)(colBase + r) * 1536 + kc + cks],      &Bt[o + tid * 8]);
      GLOBAL_TO_LDS16(&WT[(size_t)(colBase + r + 64) * 1536 + kc + cks], &Bt[o + 2048 + tid * 8]);
    }
    __syncthreads();
#pragma unroll
    for (int s = 0; s < 2; ++s) {
      const int o = s * 4096;
      half8 af[4], bf[4];
#pragma unroll
      for (int i = 0; i < 4; ++i)
        af[i] = *(const half8*)&At[o + (wr + i * 16 + fr) * 32 + qx];
#pragma unroll
      for (int j = 0; j < 4; ++j)
        bf[j] = *(const half8*)&Bt[o + (wc + j * 16 + fr) * 32 + qx];
#pragma unroll
      for (int i = 0; i < 4; ++i)
#pragma unroll
        for (int j = 0; j < 4; ++j)
          acc[i][j] = __builtin_amdgcn_mfma_f32_16x16x32_f16(af[i], bf[j], acc[i][j], 0, 0, 0);
    }
    __syncthreads();
  }
  float sc[4], of[4];
#pragma unroll
  for (int j = 0; j < 4; ++j) {
    int c = colBase + wc + j * 16 + fr;
    float s = g2[c] * rsqrtf(v2[c] + EPSV);
    sc[j] = s;
    of[j] = (cb[c] - m2[c]) * s + b2[c];
  }
#pragma unroll
  for (int i = 0; i < 4; ++i) {
    const int R0r = rowBase + wr + i * 16 + q * 4;
#pragma unroll
    for (int rg = 0; rg < 4; ++rg) {
      float* dst = &Y[(size_t)(R0r + rg) * OUTC + colBase + wc + fr];
#pragma unroll
      for (int j = 0; j < 4; ++j)
        dst[j * 16] = fmaxf(fmaf(acc[i][j][rg], sc[j], of[j]), 0.0f);
    }
  }
}

// ---------------------------------------------------------------------------
extern "C" void kernel_launch(void* const* d_in, const int* in_sizes, int n_in,
                              void* d_out, int out_size, void* d_ws, size_t ws_size,
                              hipStream_t stream) {
  const float* x     = (const float*)d_in[0];
  const float* adj   = (const float*)d_in[1];
  const float* gc_w  = (const float*)d_in[2];
  const float* gc_b  = (const float*)d_in[3];
  const float* bn1_g = (const float*)d_in[4];
  const float* bn1_b = (const float*)d_in[5];
  const float* bn1_m = (const float*)d_in[6];
  const float* bn1_v = (const float*)d_in[7];
  const float* gat_w = (const float*)d_in[8];
  const float* conv_w= (const float*)d_in[9];
  const float* conv_b= (const float*)d_in[10];
  const float* bn2_g = (const float*)d_in[11];
  const float* bn2_b = (const float*)d_in[12];
  const float* bn2_m = (const float*)d_in[13];
  const float* bn2_v = (const float*)d_in[14];
  float* out = (float*)d_out;

  char* ws = (char*)d_ws;
  _Float16* AXh = (_Float16*)(ws + 0);          // 8 MB [16384,256]
  _Float16* AXl = (_Float16*)(ws + 16777216);   // 8 MB
  _Float16* HHh = (_Float16*)(ws + 0);          // reuse after AX dead
  _Float16* XTh = (_Float16*)(ws + 33554432);   // 8 MB [32][256][512]
  _Float16* XTl = (_Float16*)(ws + 41943040);   // 8 MB
  _Float16* Gh  = (_Float16*)(ws + 33554432);   // reuse after XT dead
  _Float16* Gl  = (_Float16*)(ws + 50331648);
  _Float16* OP  = (_Float16*)(ws + 67108864);
  _Float16* WT  = (_Float16*)(ws + 83951616);
  _Float16* ADJh= (_Float16*)(ws + 85524480);
  _Float16* ADJl= (_Float16*)(ws + 86048768);
  _Float16* GWh = (_Float16*)(ws + 86573056);
  _Float16* GWl = (_Float16*)(ws + 86835200);
  _Float16* GAh = (_Float16*)(ws + 87097344);
  _Float16* GAl = (_Float16*)(ws + 87621632);

  // HHT placement: fused path needs a region NOT aliasing Gh/Gl (k_hh reads
  // G while writing HHT). If the workspace has room past the static
  // allocations, put HHT there and fuse; else fall back to separate k_vt
  // (HHT over dead G region at +33554432 — G is dead only after k_hh).
  const bool fused = ws_size >= (size_t)(88145920 + 16777216);
  _Float16* HHT = fused ? (_Float16*)(ws + 88145920)
                        : (_Float16*)(ws + 33554432);

  k_prep<<<5760, 256, 0, stream>>>(adj, gc_w, gat_w, conv_w,
                                   ADJh, ADJl, GWh, GWl, GAh, GAl, WT, OP);
  k_xsplit_t<<<1024, 256, 0, stream>>>(x, XTh, XTl);
  k_ax<<<dim3(4, 128), 256, 0, stream>>>(ADJh, ADJl, XTh, XTl, AXh, AXl);
  k_gcn2<<<dim3(4, 128), 256, 0, stream>>>(AXh, AXl, GWh, GWl, gc_b,
                                           bn1_g, bn1_b, bn1_m, bn1_v, Gh, Gl);
  if (fused) {
    k_hh<<<dim3(4, 128), 256, 0, stream>>>(Gh, Gl, GAh, GAl, HHh, HHT);
  } else {
    k_hh<<<dim3(4, 128), 256, 0, stream>>>(Gh, Gl, GAh, GAl, HHh,
                                           (_Float16*)nullptr);
    k_vt<<<512, 256, 0, stream>>>(HHh, HHT);
  }
  k_attn<<<512, 256, 0, stream>>>(HHh, HHT, OP);
  k_conv_mfma<<<dim3(4, 128), 256, 0, stream>>>(OP, WT, conv_b,
                                                bn2_g, bn2_b, bn2_m, bn2_v, out);
}